// Round 8
// baseline (688.272 us; speedup 1.0000x reference)
//
#include <hip/hip_runtime.h>
#include <hip/hip_bf16.h>

#define NN 10000
#define EE 120000
#define E_PAD 120064   // 938 * 128
#define NTILES 938     // E_PAD / 128

typedef __bf16 bf16_t;
typedef __bf16 bf16x8 __attribute__((ext_vector_type(8)));
typedef float f32x4 __attribute__((ext_vector_type(4)));

static __device__ __forceinline__ int clampi(int v) {
    return v < 0 ? 0 : (v >= NN ? NN - 1 : v);
}

// async global->LDS, 16B per lane (m97 structure)
static __device__ __forceinline__ void gld_lds16(const bf16_t* g, bf16_t* l) {
    __builtin_amdgcn_global_load_lds(
        (const __attribute__((address_space(1))) void*)g,
        (__attribute__((address_space(3))) void*)l,
        16, 0, 0);
}

// ---- float dtype detection -------------------------------------------------
__global__ __launch_bounds__(256) void detect_f32(const unsigned short* __restrict__ ea_raw,
                                                  int* __restrict__ flag) {
    int t = blockIdx.x * 256 + threadIdx.x;
    if (ea_raw[t] & 0x8000) atomicOr(flag, 1);
}

// ---- batched convert of all 16 float tensors to canonical fp32 ------------
#define N_FLT 16
struct CvtArgs {
    const void* src[N_FLT];
    float* dst;
    int offs[N_FLT];
    int n[N_FLT];
};

__global__ __launch_bounds__(256) void cvt_all(CvtArgs a, const int* __restrict__ isf32) {
    int tensor = blockIdx.y;
    int i = blockIdx.x * 256 + threadIdx.x;
    if (i >= a.n[tensor]) return;
    float v;
    if (*isf32) v = ((const float*)a.src[tensor])[i];
    else        v = (float)((const bf16_t*)a.src[tensor])[i];
    if (!isfinite(v)) v = 0.f;
    a.dst[a.offs[tensor] + i] = v;
}

// ---- index dtype handling (int32 vs int64) ---------------------------------
__global__ __launch_bounds__(256) void detect_idx(const int* __restrict__ ei,
                                                  int* __restrict__ flag) {
    int t = blockIdx.x * 256 + threadIdx.x;
    if (ei[2 * t + 1] != 0) atomicOr(flag, 1);
}

__global__ __launch_bounds__(256) void repack_idx(const int* __restrict__ ei,
                                                  const int* __restrict__ flag,
                                                  int* __restrict__ s,
                                                  int* __restrict__ d,
                                                  int* __restrict__ cnti) {
    int e = blockIdx.x * 256 + threadIdx.x;
    if (e >= EE) return;
    int sv, dv;
    if (*flag == 0) {   // int64
        sv = clampi(ei[2 * e]);
        dv = clampi(ei[2 * (EE + e)]);
    } else {            // int32
        sv = clampi(ei[e]);
        dv = clampi(ei[EE + e]);
    }
    s[e] = sv;
    d[e] = dv;
    atomicAdd(&cnti[dv], 1);
}

// single-block exclusive scan of cnti[NN] -> row_off[NN+1], pos copy
__global__ __launch_bounds__(256) void scan_kernel(const int* __restrict__ cnti,
                                                   int* __restrict__ row_off,
                                                   int* __restrict__ pos) {
    __shared__ int part[256];
    const int t = threadIdx.x;
    const int CH = (NN + 255) / 256;
    int s = 0;
    for (int i = 0; i < CH; ++i) {
        int idx = t * CH + i;
        if (idx < NN) s += cnti[idx];
    }
    part[t] = s;
    __syncthreads();
    for (int off = 1; off < 256; off <<= 1) {
        int tmp = (t >= off) ? part[t - off] : 0;
        __syncthreads();
        part[t] += tmp;
        __syncthreads();
    }
    int run = part[t] - s;
    for (int i = 0; i < CH; ++i) {
        int idx = t * CH + i;
        if (idx < NN) {
            row_off[idx] = run;
            pos[idx] = run;
            run += cnti[idx];
        }
    }
    if (t == 255) row_off[NN] = run;
}

// rank[e] = dst-sorted position of edge e; src_s[p] = src of sorted edge p
__global__ __launch_bounds__(256) void scatter_rank(const int* __restrict__ dst,
                                                    const int* __restrict__ src,
                                                    int* __restrict__ pos,
                                                    int* __restrict__ rank,
                                                    int* __restrict__ src_s) {
    int e = blockIdx.x * 256 + threadIdx.x;
    if (e >= E_PAD) return;
    if (e >= EE) { rank[e] = e; return; }
    int p = atomicAdd(&pos[dst[e]], 1);
    rank[e] = p;
    src_s[p] = src[e];
}

// ---- prep kernels (canonical fp32 in) --------------------------------------

// Bt[n][k] = B[k][n]  (permute=1: k3 output cols reordered to [out][in])
__global__ __launch_bounds__(256) void transpose_bt(const float* __restrict__ B,
                                                    bf16_t* __restrict__ Bt, int K, int N,
                                                    int permute) {
    int idx = blockIdx.x * 256 + threadIdx.x;
    if (idx >= K * N) return;
    int n = idx / K, k = idx - n * K;
    int c = permute ? (((n & 31) << 5) | (n >> 5)) : n;
    Bt[idx] = (bf16_t)B[k * N + c];
}

__global__ __launch_bounds__(256) void permute_bias(const float* __restrict__ b,
                                                    float* __restrict__ bp) {
    int n = blockIdx.x * 256 + threadIdx.x;
    bp[n] = b[((n & 31) << 5) | (n >> 5)];
}

// h0 = x @ fc1_w + fc1_b
__global__ __launch_bounds__(256) void h0_kernel(const float* __restrict__ x,
                                                 const float* __restrict__ w,
                                                 const float* __restrict__ b,
                                                 float* __restrict__ h) {
    int gid = blockIdx.x * 256 + threadIdx.x;
    int n = gid >> 5, o = gid & 31;
    float acc = b[o];
#pragma unroll
    for (int j = 0; j < 6; ++j) acc += x[n * 6 + j] * w[j * 32 + o];
    h[gid] = acc;
}

// h1_c[r,:] = relu(edge_attr[e0+r,:] @ k1_w + k1_b)
__global__ __launch_bounds__(256) void h1_chunk(const float* __restrict__ ea,
                                                const float* __restrict__ k1w,
                                                const float* __restrict__ k1b,
                                                bf16_t* __restrict__ h1, int e0) {
    __shared__ float wk[6 * 128];
    __shared__ float bk[128];
    for (int i = threadIdx.x; i < 768; i += 256) wk[i] = k1w[i];
    if (threadIdx.x < 128) bk[threadIdx.x] = k1b[threadIdx.x];
    __syncthreads();
    int gid = blockIdx.x * 256 + threadIdx.x;
    int r = gid >> 7, o = gid & 127;
    int e = e0 + r;
    if (e >= EE) { h1[gid] = (bf16_t)0.f; return; }
    float acc = bk[o];
#pragma unroll
    for (int j = 0; j < 6; ++j) acc += ea[e * 6 + j] * wk[j * 128 + o];
    h1[gid] = (bf16_t)fmaxf(acc, 0.f);
}

// ---- MFMA GEMM:  C[M,Nd] = act(A[M,K] @ Bt[Nd,K]^T + bias) ----------------
__global__ __launch_bounds__(256) void gemm_bt(const bf16_t* __restrict__ A,
                                               const bf16_t* __restrict__ Bt,
                                               const float* __restrict__ bias,
                                               bf16_t* __restrict__ C,
                                               const int* __restrict__ rank,
                                               int K, int Nd, int relu,
                                               int perm, int m_base) {
    __shared__ bf16_t As[128 * 32];
    __shared__ bf16_t Bs[128 * 32];
    const int t = threadIdx.x;
    const int lane = t & 63;
    const int wave = t >> 6;
    const int wm = wave >> 1, wn = wave & 1;
    const long m0 = (long)blockIdx.x * 128;
    const int n0 = blockIdx.y * 128;

    f32x4 acc[4][4];
#pragma unroll
    for (int i = 0; i < 4; ++i)
#pragma unroll
        for (int j = 0; j < 4; ++j) acc[i][j] = f32x4{0.f, 0.f, 0.f, 0.f};

    const int ar = t >> 2;
    const int ac = (t & 3) * 8;
    const bf16_t* gA0 = A + (m0 + ar) * (long)K + ac;
    const bf16_t* gA1 = A + (m0 + 64 + ar) * (long)K + ac;
    const bf16_t* gB0 = Bt + (long)(n0 + ar) * K + ac;
    const bf16_t* gB1 = Bt + (long)(n0 + 64 + ar) * K + ac;
    bf16_t* lA0 = &As[t * 8];
    bf16_t* lA1 = &As[2048 + t * 8];
    bf16_t* lB0 = &Bs[t * 8];
    bf16_t* lB1 = &Bs[2048 + t * 8];

    const int mrow = wm * 64 + (lane & 15);
    const int nrow = wn * 64 + (lane & 15);
    const int koff = (lane >> 4) * 8;

    for (int k0 = 0; k0 < K; k0 += 32) {
        gld_lds16(gA0 + k0, lA0);
        gld_lds16(gA1 + k0, lA1);
        gld_lds16(gB0 + k0, lB0);
        gld_lds16(gB1 + k0, lB1);
        __syncthreads();

        bf16x8 af[4], bfr[4];
#pragma unroll
        for (int i = 0; i < 4; ++i) af[i] = *(const bf16x8*)&As[(mrow + i * 16) * 32 + koff];
#pragma unroll
        for (int j = 0; j < 4; ++j) bfr[j] = *(const bf16x8*)&Bs[(nrow + j * 16) * 32 + koff];
#pragma unroll
        for (int i = 0; i < 4; ++i)
#pragma unroll
            for (int j = 0; j < 4; ++j)
                acc[i][j] = __builtin_amdgcn_mfma_f32_16x16x32_bf16(af[i], bfr[j], acc[i][j], 0, 0, 0);
        __syncthreads();
    }

    const int rbase = (lane >> 4) * 4;
    const int cidx = lane & 15;
#pragma unroll
    for (int i = 0; i < 4; ++i) {
#pragma unroll
        for (int r = 0; r < 4; ++r) {
            long row = m0 + wm * 64 + i * 16 + rbase + r;
            long crow = perm ? (long)rank[m_base + row] : row;
#pragma unroll
            for (int j = 0; j < 4; ++j) {
                int col = n0 + wn * 64 + j * 16 + cidx;
                float v = acc[i][j][r] + bias[col];
                if (relu) v = fmaxf(v, 0.f);
                C[crow * Nd + col] = (bf16_t)v;
            }
        }
    }
}

// ---- per-layer stage 1: msg_s[p,:] = h[src_s[p]] @ wt[p]  (one wave/edge) --
// wt row layout [out=32][in=32]. Lane l: o = l&31, ihalf = l>>5.
// Lane reads wt[p, o, ihalf*16 .. +16) = 32B at offset o*32 + ihalf*16 —
// the 64 lanes cover the full contiguous 2KB row (coalesced).
// rev=1: process blocks in reverse order (L3-friendly alternation).
__global__ __launch_bounds__(256) void edge_msg(const float* __restrict__ h,
                                                const bf16_t* __restrict__ wt,
                                                const int* __restrict__ src_s,
                                                bf16_t* __restrict__ msg,
                                                int rev) {
    int b = rev ? (gridDim.x - 1 - blockIdx.x) : blockIdx.x;
    int wv = threadIdx.x >> 6, lane = threadIdx.x & 63;
    int p = b * 4 + wv;
    if (p >= EE) return;
    const int o = lane & 31, ihalf = lane >> 5;

    int s = src_s[p];
    const float4* hp = (const float4*)(h + (size_t)s * 32 + ihalf * 16);
    float4 ha = hp[0], hb = hp[1], hcv = hp[2], hd = hp[3];
    const bf16x8* wp = (const bf16x8*)(wt + (size_t)p * 1024 + o * 32 + ihalf * 16);
    bf16x8 w0 = wp[0], w1 = wp[1];

    float acc = ha.x * (float)w0[0] + ha.y * (float)w0[1]
              + ha.z * (float)w0[2] + ha.w * (float)w0[3]
              + hb.x * (float)w0[4] + hb.y * (float)w0[5]
              + hb.z * (float)w0[6] + hb.w * (float)w0[7]
              + hcv.x * (float)w1[0] + hcv.y * (float)w1[1]
              + hcv.z * (float)w1[2] + hcv.w * (float)w1[3]
              + hd.x * (float)w1[4] + hd.y * (float)w1[5]
              + hd.z * (float)w1[6] + hd.w * (float)w1[7];
    acc += __shfl_xor(acc, 32, 64);
    if (ihalf == 0) msg[(size_t)p * 32 + o] = (bf16_t)acc;   // 64B coalesced
}

// ---- per-layer stage 2: CSR reduce over msg + fused root/bias/act ----------
// one wave per node; lane l: o = l&31, half = l>>5 strides the edge range.
__global__ __launch_bounds__(256) void reduce_update(const float* __restrict__ h,
                                                     const bf16_t* __restrict__ msg,
                                                     const int* __restrict__ row_off,
                                                     const float* __restrict__ rw,
                                                     const float* __restrict__ cb,
                                                     float* __restrict__ hout, int relu) {
    __shared__ float rws[1024];
    for (int i = threadIdx.x; i < 1024; i += 256) rws[i] = rw[i];
    __syncthreads();
    const int wv = threadIdx.x >> 6, lane = threadIdx.x & 63;
    const int n = blockIdx.x * 4 + wv;
    if (n >= NN) return;
    const int o = lane & 31, half = lane >> 5;

    const int b0 = row_off[n], b1 = row_off[n + 1];
    float acc = 0.f;
    for (int k = b0 + half; k < b1; k += 2)
        acc += (float)msg[(size_t)k * 32 + o];
    acc += __shfl_xor(acc, 32, 64);

    if (half == 0) {
        // root term: sum_j h[n][j] * rw[j][o]
        const float* hrow = h + (size_t)n * 32;
        float rp = 0.f;
#pragma unroll
        for (int j = 0; j < 32; ++j) rp += hrow[j] * rws[j * 32 + o];
        float den = fmaxf((float)(b1 - b0), 1.f);
        float v = acc / den + rp + cb[o];
        if (relu) v = fmaxf(v, 0.f);
        hout[(size_t)n * 32 + o] = v;
    }
}

// ---- fallback (ws too small for full w_e): per-edge wave + atomics ---------
__global__ __launch_bounds__(256) void edge_scatter(const float* __restrict__ h,
                                                    const bf16_t* __restrict__ wt,
                                                    const int* __restrict__ src,
                                                    const int* __restrict__ dst,
                                                    float* __restrict__ aggr,
                                                    int e0, int e1) {
    int wv = threadIdx.x >> 6, lane = threadIdx.x & 63;
    int e = e0 + blockIdx.x * 4 + wv;
    if (e >= e1) return;
    int s = src[e], d = dst[e];
    int o = lane & 31, ihalf = lane >> 5;
    const float4* hp = (const float4*)(h + (size_t)s * 32 + ihalf * 16);
    float4 ha = hp[0], hb = hp[1], hcv = hp[2], hd = hp[3];
    const bf16x8* wp = (const bf16x8*)(wt + (size_t)(e - e0) * 1024 + o * 32 + ihalf * 16);
    bf16x8 w0 = wp[0], w1 = wp[1];
    float acc = ha.x * (float)w0[0] + ha.y * (float)w0[1]
              + ha.z * (float)w0[2] + ha.w * (float)w0[3]
              + hb.x * (float)w0[4] + hb.y * (float)w0[5]
              + hb.z * (float)w0[6] + hb.w * (float)w0[7]
              + hcv.x * (float)w1[0] + hcv.y * (float)w1[1]
              + hcv.z * (float)w1[2] + hcv.w * (float)w1[3]
              + hd.x * (float)w1[4] + hd.y * (float)w1[5]
              + hd.z * (float)w1[6] + hd.w * (float)w1[7];
    acc += __shfl_xor(acc, 32, 64);
    if (ihalf == 0) atomicAdd(&aggr[(size_t)d * 32 + o], acc);
}

__global__ __launch_bounds__(256) void node_update(const float* __restrict__ hin,
                                                   const float* __restrict__ aggr,
                                                   const int* __restrict__ cnti,
                                                   const float* __restrict__ rw,
                                                   const float* __restrict__ cb,
                                                   float* __restrict__ hout, int relu) {
    __shared__ float rws[32 * 32];
    for (int i = threadIdx.x; i < 1024; i += 256) rws[i] = rw[i];
    __syncthreads();
    int gid = blockIdx.x * 256 + threadIdx.x;
    int n = gid >> 5, o = gid & 31;
    float den = fmaxf((float)cnti[n], 1.f);
    float acc = aggr[gid] / den + cb[o];
    const float* hrow = hin + (size_t)n * 32;
#pragma unroll
    for (int j = 0; j < 32; ++j) acc += hrow[j] * rws[j * 32 + o];
    if (relu) acc = fmaxf(acc, 0.f);
    hout[gid] = acc;
}

// out = relu(h @ fc2 + b2) @ fc3 + b3
__global__ __launch_bounds__(256) void head_kernel(const float* __restrict__ h,
                                                   const float* __restrict__ w2,
                                                   const float* __restrict__ b2,
                                                   const float* __restrict__ w3,
                                                   const float* __restrict__ b3,
                                                   void* __restrict__ out,
                                                   const int* __restrict__ isf32) {
    int wave = threadIdx.x >> 6, lane = threadIdx.x & 63;
    int n = blockIdx.x * 4 + wave;
    if (n >= NN) return;
    const float* hrow = h + (size_t)n * 32;
    float hr[32];
#pragma unroll
    for (int j = 0; j < 32; ++j) hr[j] = hrow[j];
    int o0 = lane * 2, o1 = lane * 2 + 1;
    float v0 = b2[o0], v1 = b2[o1];
#pragma unroll
    for (int j = 0; j < 32; ++j) {
        float hj = hr[j];
        v0 += hj * w2[j * 128 + o0];
        v1 += hj * w2[j * 128 + o1];
    }
    float y = fmaxf(v0, 0.f) * w3[o0] + fmaxf(v1, 0.f) * w3[o1];
#pragma unroll
    for (int m = 1; m < 64; m <<= 1) y += __shfl_xor(y, m, 64);
    if (lane == 0) {
        float r = y + b3[0];
        if (*isf32) ((float*)out)[n] = r;
        else        ((bf16_t*)out)[n] = (bf16_t)r;
    }
}

// ---------------------------------------------------------------------------

extern "C" void kernel_launch(void* const* d_in, const int* in_sizes, int n_in,
                              void* d_out, int out_size, void* d_ws, size_t ws_size,
                              hipStream_t stream) {
    const int* ei = (const int*)d_in[1];

    char* ws = (char*)d_ws;
    size_t off = 0;
    auto alignup = [](size_t b) { return (b + 255) & ~(size_t)255; };
    auto alloc = [&](size_t bytes) {
        char* p = ws + off;
        off += alignup(bytes);
        return (void*)p;
    };
    float*  h_a   = (float*)alloc((size_t)NN * 32 * 4);
    float*  h_b   = (float*)alloc((size_t)NN * 32 * 4);
    int*    cnti  = (int*)alloc((size_t)NN * 4);
    int*    rowo  = (int*)alloc((size_t)(NN + 1) * 4);
    int*    pos   = (int*)alloc((size_t)NN * 4);
    int*    f32fl = (int*)alloc(256);
    int*    idxfl = (int*)alloc(256);
    int*    srcb  = (int*)alloc((size_t)EE * 4);
    int*    dstb  = (int*)alloc((size_t)EE * 4);
    int*    rankb = (int*)alloc((size_t)E_PAD * 4);
    int*    src_s = (int*)alloc((size_t)E_PAD * 4);
    bf16_t* k2t   = (bf16_t*)alloc(256 * 128 * 2);
    bf16_t* k3t   = (bf16_t*)alloc(1024 * 256 * 2);
    float*  k3bp  = (float*)alloc(1024 * 4);

    static const int fidx[N_FLT] = {0, 2, 3, 4, 5, 6, 7, 8, 9, 10, 11, 12, 13, 14, 15, 16};
    static const int fn[N_FLT]   = {NN * 6, EE * 6, 192, 32, 768, 128, 32768, 256,
                                    262144, 1024, 1024, 32, 4096, 128, 128, 1};
    int foffs[N_FLT];
    int tot = 0;
    for (int i = 0; i < N_FLT; ++i) { foffs[i] = tot; tot += fn[i]; }
    float* canon = (float*)alloc((size_t)tot * 4);
    const float* c_x    = canon + foffs[0];
    const float* c_ea   = canon + foffs[1];
    const float* c_fc1w = canon + foffs[2];
    const float* c_fc1b = canon + foffs[3];
    const float* c_k1w  = canon + foffs[4];
    const float* c_k1b  = canon + foffs[5];
    const float* c_k2w  = canon + foffs[6];
    const float* c_k2b  = canon + foffs[7];
    const float* c_k3w  = canon + foffs[8];
    const float* c_k3b  = canon + foffs[9];
    const float* c_rw   = canon + foffs[10];
    const float* c_cb   = canon + foffs[11];
    const float* c_fc2w = canon + foffs[12];
    const float* c_fc2b = canon + foffs[13];
    const float* c_fc3w = canon + foffs[14];
    const float* c_fc3b = canon + foffs[15];
    size_t fixed_end = off;

    // ---- mode selection (constant per harness -> graph-safe) ----
    const size_t sz_we  = (size_t)E_PAD * 1024 * 2;    // 246 MB
    const size_t sz_msg = (size_t)E_PAD * 32 * 2;      // 7.7 MB
    auto scratch_sz = [&](int Tq) {
        size_t prep = alignup((size_t)Tq * 128 * 128 * 2) + alignup((size_t)Tq * 128 * 256 * 2);
        return prep > alignup(sz_msg) ? prep : alignup(sz_msg);
    };
    auto chunk_need = [&](int Tq) {
        return fixed_end + sz_we + scratch_sz(Tq) + 1024;
    };
    int mode, T;
    if (ws_size >= chunk_need(NTILES))      { mode = 2; T = NTILES; }
    else if (ws_size >= chunk_need(128))    { mode = 1; T = 128; }
    else if (ws_size >= chunk_need(64))     { mode = 1; T = 64; }
    else                                    { mode = 0; T = 0; }

    bf16_t *h1_b, *h2_b, *w_e, *msg_s = nullptr;
    float* aggr = nullptr;
    if (mode >= 1) {
        char* scratch = (char*)alloc(scratch_sz(T));
        h1_b  = (bf16_t*)scratch;
        h2_b  = (bf16_t*)(scratch + alignup((size_t)T * 128 * 128 * 2));
        msg_s = (bf16_t*)scratch;               // aliased: prep done before layers
        w_e   = (bf16_t*)alloc(sz_we);
    } else {
        aggr = (float*)alloc((size_t)NN * 32 * 4);
        size_t per_tile = (size_t)128 * 128 * 2 + 128 * 256 * 2 + 128 * 1024 * 2;
        size_t avail = ws_size > off + 4096 ? ws_size - off - 4096 : per_tile;
        long t = (long)(avail / per_tile);
        if (t > NTILES) t = NTILES;
        if (t < 1) t = 1;
        T = (int)t;
        h1_b = (bf16_t*)alloc((size_t)T * 128 * 128 * 2);
        h2_b = (bf16_t*)alloc((size_t)T * 128 * 256 * 2);
        w_e  = (bf16_t*)alloc((size_t)T * 128 * 1024 * 2);
    }

    hipMemsetAsync(cnti, 0, (size_t)NN * 4, stream);
    hipMemsetAsync(f32fl, 0, 256, stream);
    hipMemsetAsync(idxfl, 0, 256, stream);

    detect_f32<<<32, 256, 0, stream>>>((const unsigned short*)d_in[2], f32fl);

    CvtArgs ca;
    for (int i = 0; i < N_FLT; ++i) {
        ca.src[i] = d_in[fidx[i]];
        ca.offs[i] = foffs[i];
        ca.n[i] = fn[i];
    }
    ca.dst = canon;
    {
        dim3 g((EE * 6 + 255) / 256, N_FLT);
        cvt_all<<<g, 256, 0, stream>>>(ca, f32fl);
    }

    detect_idx<<<16, 256, 0, stream>>>(ei, idxfl);
    repack_idx<<<(EE + 255) / 256, 256, 0, stream>>>(ei, idxfl, srcb, dstb, cnti);
    scan_kernel<<<1, 256, 0, stream>>>(cnti, rowo, pos);
    scatter_rank<<<(E_PAD + 255) / 256, 256, 0, stream>>>(dstb, srcb, pos, rankb, src_s);

    transpose_bt<<<(128 * 256 + 255) / 256, 256, 0, stream>>>(c_k2w, k2t, 128, 256, 0);
    transpose_bt<<<(256 * 1024 + 255) / 256, 256, 0, stream>>>(c_k3w, k3t, 256, 1024, 1);
    permute_bias<<<4, 256, 0, stream>>>(c_k3b, k3bp);
    h0_kernel<<<NN * 32 / 256, 256, 0, stream>>>(c_x, c_fc1w, c_fc1b, h_a);

    auto prep_chunk = [&](int tile0, int tiles, bf16_t* c_dst, int perm) {
        int rows = tiles * 128;
        h1_chunk<<<rows * 128 / 256, 256, 0, stream>>>(c_ea, c_k1w, c_k1b, h1_b, tile0 * 128);
        dim3 g2(tiles, 2);
        gemm_bt<<<g2, 256, 0, stream>>>(h1_b, k2t, c_k2b, h2_b, rankb, 128, 256, 1, 0, 0);
        dim3 g3(tiles, 8);
        gemm_bt<<<g3, 256, 0, stream>>>(h2_b, k3t, k3bp, c_dst, rankb, 256, 1024, 0,
                                        perm, tile0 * 128);
    };

    float* hc = h_a;
    float* hn = h_b;
    if (mode >= 1) {
        for (int t0 = 0; t0 < NTILES; t0 += T) {
            int tl = (t0 + T <= NTILES) ? T : (NTILES - t0);
            prep_chunk(t0, tl, w_e, 1);
        }
        for (int d = 0; d < 4; ++d) {
            edge_msg<<<(EE + 3) / 4, 256, 0, stream>>>(hc, w_e, src_s, msg_s, d & 1);
            reduce_update<<<(NN + 3) / 4, 256, 0, stream>>>(hc, msg_s, rowo, c_rw, c_cb,
                                                            hn, (d < 3) ? 1 : 0);
            float* tmp = hc; hc = hn; hn = tmp;
        }
    } else {
        for (int d = 0; d < 4; ++d) {
            hipMemsetAsync(aggr, 0, (size_t)NN * 32 * 4, stream);
            for (int t0 = 0; t0 < NTILES; t0 += T) {
                int tl = (t0 + T <= NTILES) ? T : (NTILES - t0);
                prep_chunk(t0, tl, w_e, 0);
                int e0 = t0 * 128;
                int e1 = e0 + tl * 128; if (e1 > EE) e1 = EE;
                if (e1 > e0)
                    edge_scatter<<<(e1 - e0 + 3) / 4, 256, 0, stream>>>(hc, w_e, srcb, dstb,
                                                                        aggr, e0, e1);
            }
            node_update<<<NN * 32 / 256, 256, 0, stream>>>(hc, aggr, cnti, c_rw, c_cb, hn,
                                                           (d < 3) ? 1 : 0);
            float* tmp = hc; hc = hn; hn = tmp;
        }
    }

    head_kernel<<<(NN + 3) / 4, 256, 0, stream>>>(hc, c_fc2w, c_fc2b, c_fc3w, c_fc3b,
                                                  d_out, f32fl);
}

// Round 9
// 616.331 us; speedup vs baseline: 1.1167x; 1.1167x over previous
//
#include <hip/hip_runtime.h>
#include <hip/hip_bf16.h>

#define NN 10000
#define EE 120000
#define E_PAD 120064   // 938 * 128
#define NTILES 938     // E_PAD / 128

#define H1S 152        // h1 LDS row stride (elems): (152/2)%32=12 -> 2-way-free
#define H2S 280        // h2 LDS row stride (elems): (280/2)%32=12 -> 2-way-free

typedef __bf16 bf16_t;
typedef __bf16 bf16x8 __attribute__((ext_vector_type(8)));
typedef float f32x4 __attribute__((ext_vector_type(4)));

static __device__ __forceinline__ int clampi(int v) {
    return v < 0 ? 0 : (v >= NN ? NN - 1 : v);
}

// ---- float dtype detection -------------------------------------------------
__global__ __launch_bounds__(256) void detect_f32(const unsigned short* __restrict__ ea_raw,
                                                  int* __restrict__ flag) {
    int t = blockIdx.x * 256 + threadIdx.x;
    if (ea_raw[t] & 0x8000) atomicOr(flag, 1);
}

// ---- batched convert of all 16 float tensors to canonical fp32 (flat grid) -
#define N_FLT 16
struct CvtArgs {
    const void* src[N_FLT];
    float* dst;
    int offs[N_FLT];
    int n[N_FLT];
    int tot;
};

__global__ __launch_bounds__(256) void cvt_flat(CvtArgs a, const int* __restrict__ isf32) {
    int i = blockIdx.x * 256 + threadIdx.x;
    if (i >= a.tot) return;
    int t = 0;
#pragma unroll
    for (int k = 1; k < N_FLT; ++k) if (i >= a.offs[k]) t = k;
    int il = i - a.offs[t];
    float v;
    if (*isf32) v = ((const float*)a.src[t])[il];
    else        v = (float)((const bf16_t*)a.src[t])[il];
    if (!isfinite(v)) v = 0.f;
    a.dst[i] = v;
}

// ---- index dtype handling (int32 vs int64) ---------------------------------
__global__ __launch_bounds__(256) void detect_idx(const int* __restrict__ ei,
                                                  int* __restrict__ flag) {
    int t = blockIdx.x * 256 + threadIdx.x;
    if (ei[2 * t + 1] != 0) atomicOr(flag, 1);
}

__global__ __launch_bounds__(256) void repack_idx(const int* __restrict__ ei,
                                                  const int* __restrict__ flag,
                                                  int* __restrict__ s,
                                                  int* __restrict__ d,
                                                  int* __restrict__ cnti) {
    int e = blockIdx.x * 256 + threadIdx.x;
    if (e >= EE) return;
    int sv, dv;
    if (*flag == 0) {   // int64
        sv = clampi(ei[2 * e]);
        dv = clampi(ei[2 * (EE + e)]);
    } else {            // int32
        sv = clampi(ei[e]);
        dv = clampi(ei[EE + e]);
    }
    s[e] = sv;
    d[e] = dv;
    atomicAdd(&cnti[dv], 1);
}

// single-block exclusive scan of cnti[NN] -> row_off[NN+1], pos copy
__global__ __launch_bounds__(256) void scan_kernel(const int* __restrict__ cnti,
                                                   int* __restrict__ row_off,
                                                   int* __restrict__ pos) {
    __shared__ int part[256];
    const int t = threadIdx.x;
    const int CH = (NN + 255) / 256;
    int s = 0;
    for (int i = 0; i < CH; ++i) {
        int idx = t * CH + i;
        if (idx < NN) s += cnti[idx];
    }
    part[t] = s;
    __syncthreads();
    for (int off = 1; off < 256; off <<= 1) {
        int tmp = (t >= off) ? part[t - off] : 0;
        __syncthreads();
        part[t] += tmp;
        __syncthreads();
    }
    int run = part[t] - s;
    for (int i = 0; i < CH; ++i) {
        int idx = t * CH + i;
        if (idx < NN) {
            row_off[idx] = run;
            pos[idx] = run;
            run += cnti[idx];
        }
    }
    if (t == 255) row_off[NN] = run;
}

// rank[e] = dst-sorted position of edge e; src_s[p] = src of sorted edge p
__global__ __launch_bounds__(256) void scatter_rank(const int* __restrict__ dst,
                                                    const int* __restrict__ src,
                                                    int* __restrict__ pos,
                                                    int* __restrict__ rank,
                                                    int* __restrict__ src_s) {
    int e = blockIdx.x * 256 + threadIdx.x;
    if (e >= E_PAD) return;
    if (e >= EE) { rank[e] = e; return; }
    int p = atomicAdd(&pos[dst[e]], 1);
    rank[e] = p;
    src_s[p] = src[e];
}

// ---- small prep ------------------------------------------------------------

// Bt[n][k] = B[k][n]  (permute=1: k3 output cols reordered to [out][in])
__global__ __launch_bounds__(256) void transpose_bt(const float* __restrict__ B,
                                                    bf16_t* __restrict__ Bt, int K, int N,
                                                    int permute) {
    int idx = blockIdx.x * 256 + threadIdx.x;
    if (idx >= K * N) return;
    int n = idx / K, k = idx - n * K;
    int c = permute ? (((n & 31) << 5) | (n >> 5)) : n;
    Bt[idx] = (bf16_t)B[k * N + c];
}

__global__ __launch_bounds__(256) void permute_bias(const float* __restrict__ b,
                                                    float* __restrict__ bp) {
    int n = blockIdx.x * 256 + threadIdx.x;
    bp[n] = b[((n & 31) << 5) | (n >> 5)];
}

// h0 = x @ fc1_w + fc1_b
__global__ __launch_bounds__(256) void h0_kernel(const float* __restrict__ x,
                                                 const float* __restrict__ w,
                                                 const float* __restrict__ b,
                                                 float* __restrict__ h) {
    int gid = blockIdx.x * 256 + threadIdx.x;
    int n = gid >> 5, o = gid & 31;
    float acc = b[o];
#pragma unroll
    for (int j = 0; j < 6; ++j) acc += x[n * 6 + j] * w[j * 32 + o];
    h[gid] = acc;
}

// ---- FUSED PREP: per 128-edge tile: h1 (VALU->LDS) -> k2 (MFMA, h2 in LDS)
// -> k3 (MFMA) -> w_e global (dst-sorted rows when perm=1).
// A-operands from LDS (padded strides); B-operands DIRECT from global (L2-hot:
// k2t 64 KB, k3t 512 KB shared by all blocks). Only 3 barriers per block.
__global__ __launch_bounds__(256) void fused_prep(const float* __restrict__ ea,
                                                  const float* __restrict__ k1w,
                                                  const float* __restrict__ k1b,
                                                  const bf16_t* __restrict__ k2t,
                                                  const float* __restrict__ k2b,
                                                  const bf16_t* __restrict__ k3t,
                                                  const float* __restrict__ k3bp,
                                                  bf16_t* __restrict__ we,
                                                  const int* __restrict__ rank,
                                                  int tile0, int perm) {
    __shared__ float  ea_s[128 * 6];
    __shared__ float  k1w_s[6 * 128];
    __shared__ float  k1b_s[128];
    __shared__ bf16_t h1_s[128 * H1S];
    __shared__ bf16_t h2_s[128 * H2S];

    const int t = threadIdx.x;
    const int tile = tile0 + blockIdx.x;
    const int e0 = tile * 128;

    // Phase 0: stage edge_attr tile + k1 weights
    for (int i = t; i < 768; i += 256) {
        int r = i / 6, j = i - r * 6;
        int e = e0 + r;
        ea_s[i] = (e < EE) ? ea[(size_t)e * 6 + j] : 0.f;
        k1w_s[i] = k1w[i];
    }
    if (t < 128) k1b_s[t] = k1b[t];
    __syncthreads();

    // Phase 1: h1 = relu(ea @ k1w + k1b)  -> LDS (128 x 128, stride H1S)
    {
        const int o = t & 127, rh = t >> 7;   // 64 rows each
        for (int r = rh * 64; r < rh * 64 + 64; ++r) {
            float acc = k1b_s[o];
#pragma unroll
            for (int j = 0; j < 6; ++j) acc += ea_s[r * 6 + j] * k1w_s[j * 128 + o];
            h1_s[r * H1S + o] = (bf16_t)fmaxf(acc, 0.f);
        }
    }
    __syncthreads();

    const int lane = t & 63;
    const int wave = t >> 6;
    const int wm = wave >> 1, wn = wave & 1;
    const int nr16 = lane & 15;
    const int koff = (lane >> 4) * 8;
    const int mrow = wm * 64 + nr16;
    const int rbase = (lane >> 4) * 4;

    // Phase 2: h2 = relu(h1 @ k2t^T + k2b) -> LDS (128 x 256, stride H2S)
#pragma unroll
    for (int nh = 0; nh < 2; ++nh) {
        f32x4 acc[4][4];
#pragma unroll
        for (int i = 0; i < 4; ++i)
#pragma unroll
            for (int j = 0; j < 4; ++j) acc[i][j] = f32x4{0.f, 0.f, 0.f, 0.f};
#pragma unroll
        for (int ks = 0; ks < 4; ++ks) {
            const int k0 = ks * 32;
            bf16x8 af[4], bfr[4];
#pragma unroll
            for (int i = 0; i < 4; ++i)
                af[i] = *(const bf16x8*)&h1_s[(mrow + i * 16) * H1S + k0 + koff];
#pragma unroll
            for (int j = 0; j < 4; ++j)
                bfr[j] = *(const bf16x8*)&k2t[(nh * 128 + wn * 64 + j * 16 + nr16) * 128 + k0 + koff];
#pragma unroll
            for (int i = 0; i < 4; ++i)
#pragma unroll
                for (int j = 0; j < 4; ++j)
                    acc[i][j] = __builtin_amdgcn_mfma_f32_16x16x32_bf16(af[i], bfr[j], acc[i][j], 0, 0, 0);
        }
#pragma unroll
        for (int i = 0; i < 4; ++i) {
#pragma unroll
            for (int j = 0; j < 4; ++j) {
                int col = wn * 64 + j * 16 + nr16;
                float bv = k2b[nh * 128 + col];
#pragma unroll
                for (int r = 0; r < 4; ++r) {
                    int row = wm * 64 + i * 16 + rbase + r;
                    h2_s[row * H2S + nh * 128 + col] = (bf16_t)fmaxf(acc[i][j][r] + bv, 0.f);
                }
            }
        }
    }
    __syncthreads();

    // Phase 3: w_e_tile = h2 @ k3t^T + k3bp  -> global (rank-scattered rows)
#pragma unroll 1
    for (int nt = 0; nt < 8; ++nt) {
        f32x4 acc[4][4];
#pragma unroll
        for (int i = 0; i < 4; ++i)
#pragma unroll
            for (int j = 0; j < 4; ++j) acc[i][j] = f32x4{0.f, 0.f, 0.f, 0.f};
#pragma unroll 1
        for (int ks = 0; ks < 8; ++ks) {
            const int k0 = ks * 32;
            bf16x8 af[4], bfr[4];
#pragma unroll
            for (int i = 0; i < 4; ++i)
                af[i] = *(const bf16x8*)&h2_s[(mrow + i * 16) * H2S + k0 + koff];
#pragma unroll
            for (int j = 0; j < 4; ++j)
                bfr[j] = *(const bf16x8*)&k3t[(size_t)(nt * 128 + wn * 64 + j * 16 + nr16) * 256 + k0 + koff];
#pragma unroll
            for (int i = 0; i < 4; ++i)
#pragma unroll
                for (int j = 0; j < 4; ++j)
                    acc[i][j] = __builtin_amdgcn_mfma_f32_16x16x32_bf16(af[i], bfr[j], acc[i][j], 0, 0, 0);
        }
#pragma unroll
        for (int i = 0; i < 4; ++i) {
#pragma unroll
            for (int r = 0; r < 4; ++r) {
                int lr = wm * 64 + i * 16 + rbase + r;
                long er = (long)e0 + lr;
                long crow = perm ? (long)rank[er] : (long)blockIdx.x * 128 + lr;
#pragma unroll
                for (int j = 0; j < 4; ++j) {
                    int col = nt * 128 + wn * 64 + j * 16 + nr16;
                    we[crow * 1024 + col] = (bf16_t)(acc[i][j][r] + k3bp[col]);
                }
            }
        }
    }
}

// ---- CSR layer, dst-sorted streaming w_e; one wave per node; no atomics ----
// wt rows sorted by dst: node n owns rows [row_off[n], row_off[n+1]).
// wt row layout [out=32][in=32]; lane l: o = l>>1, half = l&1.
// rev alternates traversal direction per layer (L3 reuse of the 246 MB array).
__global__ __launch_bounds__(256) void gather_stream(const float* __restrict__ h,
                                                     const bf16_t* __restrict__ wt,
                                                     const int* __restrict__ src_s,
                                                     const int* __restrict__ row_off,
                                                     const float* __restrict__ rw,
                                                     const float* __restrict__ cb,
                                                     float* __restrict__ hout,
                                                     int relu, int rev) {
    __shared__ float rws[1024];
    for (int i = threadIdx.x; i < 1024; i += 256) rws[i] = rw[i];
    __syncthreads();
    const int wv = threadIdx.x >> 6, lane = threadIdx.x & 63;
    const int nb = rev ? ((int)gridDim.x - 1 - blockIdx.x) : blockIdx.x;
    const int n = nb * 4 + wv;
    if (n >= NN) return;
    const int o = lane >> 1, half = lane & 1;

    const int b0 = row_off[n], b1 = row_off[n + 1];
    float acc = 0.f;
    if (b0 < b1) {
        int s = src_s[b0];
        const float4* hp = (const float4*)(h + (size_t)s * 32 + half * 16);
        float4 ha = hp[0], hb = hp[1], hcv = hp[2], hd = hp[3];
        const bf16x8* wp = (const bf16x8*)(wt + (size_t)b0 * 1024 + lane * 16);
        bf16x8 w0 = wp[0], w1 = wp[1];
        for (int k = b0; k + 1 < b1; ++k) {
            int s2 = src_s[k + 1];
            const float4* hp2 = (const float4*)(h + (size_t)s2 * 32 + half * 16);
            float4 na = hp2[0], nb2 = hp2[1], nc = hp2[2], nd = hp2[3];
            const bf16x8* wp2 = (const bf16x8*)(wt + (size_t)(k + 1) * 1024 + lane * 16);
            bf16x8 nw0 = wp2[0], nw1 = wp2[1];
            acc += ha.x * (float)w0[0] + ha.y * (float)w0[1]
                 + ha.z * (float)w0[2] + ha.w * (float)w0[3]
                 + hb.x * (float)w0[4] + hb.y * (float)w0[5]
                 + hb.z * (float)w0[6] + hb.w * (float)w0[7]
                 + hcv.x * (float)w1[0] + hcv.y * (float)w1[1]
                 + hcv.z * (float)w1[2] + hcv.w * (float)w1[3]
                 + hd.x * (float)w1[4] + hd.y * (float)w1[5]
                 + hd.z * (float)w1[6] + hd.w * (float)w1[7];
            ha = na; hb = nb2; hcv = nc; hd = nd; w0 = nw0; w1 = nw1;
        }
        acc += ha.x * (float)w0[0] + ha.y * (float)w0[1]
             + ha.z * (float)w0[2] + ha.w * (float)w0[3]
             + hb.x * (float)w0[4] + hb.y * (float)w0[5]
             + hb.z * (float)w0[6] + hb.w * (float)w0[7]
             + hcv.x * (float)w1[0] + hcv.y * (float)w1[1]
             + hcv.z * (float)w1[2] + hcv.w * (float)w1[3]
             + hd.x * (float)w1[4] + hd.y * (float)w1[5]
             + hd.z * (float)w1[6] + hd.w * (float)w1[7];
    }

    float rp = 0.f;
    const float4* hn = (const float4*)(h + (size_t)n * 32 + half * 16);
    float4 a = hn[0], b = hn[1], c = hn[2], dd = hn[3];
    const float* rwb = &rws[half * 16 * 32 + o];
    rp += a.x * rwb[0]   + a.y * rwb[32]  + a.z * rwb[64]  + a.w * rwb[96];
    rp += b.x * rwb[128] + b.y * rwb[160] + b.z * rwb[192] + b.w * rwb[224];
    rp += c.x * rwb[256] + c.y * rwb[288] + c.z * rwb[320] + c.w * rwb[352];
    rp += dd.x * rwb[384] + dd.y * rwb[416] + dd.z * rwb[448] + dd.w * rwb[480];

    acc += __shfl_xor(acc, 1, 64);
    rp  += __shfl_xor(rp, 1, 64);
    if (half == 0) {
        float den = fmaxf((float)(b1 - b0), 1.f);
        float v = acc / den + rp + cb[o];
        if (relu) v = fmaxf(v, 0.f);
        hout[(size_t)n * 32 + o] = v;
    }
}

// ---- fallback (ws too small for full w_e): per-edge wave + atomics ---------
__global__ __launch_bounds__(256) void edge_scatter(const float* __restrict__ h,
                                                    const bf16_t* __restrict__ wt,
                                                    const int* __restrict__ src,
                                                    const int* __restrict__ dst,
                                                    float* __restrict__ aggr,
                                                    int e0, int e1) {
    int wv = threadIdx.x >> 6, lane = threadIdx.x & 63;
    int e = e0 + blockIdx.x * 4 + wv;
    if (e >= e1) return;
    int s = src[e], d = dst[e];
    int o = lane & 31, ihalf = lane >> 5;
    const float4* hp = (const float4*)(h + (size_t)s * 32 + ihalf * 16);
    float4 ha = hp[0], hb = hp[1], hcv = hp[2], hd = hp[3];
    const bf16x8* wp = (const bf16x8*)(wt + (size_t)(e - e0) * 1024 + o * 32 + ihalf * 16);
    bf16x8 w0 = wp[0], w1 = wp[1];
    float acc = ha.x * (float)w0[0] + ha.y * (float)w0[1]
              + ha.z * (float)w0[2] + ha.w * (float)w0[3]
              + hb.x * (float)w0[4] + hb.y * (float)w0[5]
              + hb.z * (float)w0[6] + hb.w * (float)w0[7]
              + hcv.x * (float)w1[0] + hcv.y * (float)w1[1]
              + hcv.z * (float)w1[2] + hcv.w * (float)w1[3]
              + hd.x * (float)w1[4] + hd.y * (float)w1[5]
              + hd.z * (float)w1[6] + hd.w * (float)w1[7];
    acc += __shfl_xor(acc, 32, 64);
    if (ihalf == 0) atomicAdd(&aggr[(size_t)d * 32 + o], acc);
}

__global__ __launch_bounds__(256) void node_update(const float* __restrict__ hin,
                                                   const float* __restrict__ aggr,
                                                   const int* __restrict__ cnti,
                                                   const float* __restrict__ rw,
                                                   const float* __restrict__ cb,
                                                   float* __restrict__ hout, int relu) {
    __shared__ float rws[32 * 32];
    for (int i = threadIdx.x; i < 1024; i += 256) rws[i] = rw[i];
    __syncthreads();
    int gid = blockIdx.x * 256 + threadIdx.x;
    int n = gid >> 5, o = gid & 31;
    float den = fmaxf((float)cnti[n], 1.f);
    float acc = aggr[gid] / den + cb[o];
    const float* hrow = hin + (size_t)n * 32;
#pragma unroll
    for (int j = 0; j < 32; ++j) acc += hrow[j] * rws[j * 32 + o];
    if (relu) acc = fmaxf(acc, 0.f);
    hout[gid] = acc;
}

// out = relu(h @ fc2 + b2) @ fc3 + b3
__global__ __launch_bounds__(256) void head_kernel(const float* __restrict__ h,
                                                   const float* __restrict__ w2,
                                                   const float* __restrict__ b2,
                                                   const float* __restrict__ w3,
                                                   const float* __restrict__ b3,
                                                   void* __restrict__ out,
                                                   const int* __restrict__ isf32) {
    int wave = threadIdx.x >> 6, lane = threadIdx.x & 63;
    int n = blockIdx.x * 4 + wave;
    if (n >= NN) return;
    const float* hrow = h + (size_t)n * 32;
    float hr[32];
#pragma unroll
    for (int j = 0; j < 32; ++j) hr[j] = hrow[j];
    int o0 = lane * 2, o1 = lane * 2 + 1;
    float v0 = b2[o0], v1 = b2[o1];
#pragma unroll
    for (int j = 0; j < 32; ++j) {
        float hj = hr[j];
        v0 += hj * w2[j * 128 + o0];
        v1 += hj * w2[j * 128 + o1];
    }
    float y = fmaxf(v0, 0.f) * w3[o0] + fmaxf(v1, 0.f) * w3[o1];
#pragma unroll
    for (int m = 1; m < 64; m <<= 1) y += __shfl_xor(y, m, 64);
    if (lane == 0) {
        float r = y + b3[0];
        if (*isf32) ((float*)out)[n] = r;
        else        ((bf16_t*)out)[n] = (bf16_t)r;
    }
}

// ---------------------------------------------------------------------------

extern "C" void kernel_launch(void* const* d_in, const int* in_sizes, int n_in,
                              void* d_out, int out_size, void* d_ws, size_t ws_size,
                              hipStream_t stream) {
    const int* ei = (const int*)d_in[1];

    char* ws = (char*)d_ws;
    size_t off = 0;
    auto alignup = [](size_t b) { return (b + 255) & ~(size_t)255; };
    auto alloc = [&](size_t bytes) {
        char* p = ws + off;
        off += alignup(bytes);
        return (void*)p;
    };
    float*  h_a   = (float*)alloc((size_t)NN * 32 * 4);
    float*  h_b   = (float*)alloc((size_t)NN * 32 * 4);
    int*    cnti  = (int*)alloc((size_t)NN * 4);
    int*    rowo  = (int*)alloc((size_t)(NN + 1) * 4);
    int*    pos   = (int*)alloc((size_t)NN * 4);
    int*    f32fl = (int*)alloc(256);
    int*    idxfl = (int*)alloc(256);
    int*    srcb  = (int*)alloc((size_t)EE * 4);
    int*    dstb  = (int*)alloc((size_t)EE * 4);
    int*    rankb = (int*)alloc((size_t)E_PAD * 4);
    int*    src_s = (int*)alloc((size_t)E_PAD * 4);
    bf16_t* k2t   = (bf16_t*)alloc(256 * 128 * 2);
    bf16_t* k3t   = (bf16_t*)alloc(1024 * 256 * 2);
    float*  k3bp  = (float*)alloc(1024 * 4);

    static const int fidx[N_FLT] = {0, 2, 3, 4, 5, 6, 7, 8, 9, 10, 11, 12, 13, 14, 15, 16};
    static const int fn[N_FLT]   = {NN * 6, EE * 6, 192, 32, 768, 128, 32768, 256,
                                    262144, 1024, 1024, 32, 4096, 128, 128, 1};
    int foffs[N_FLT];
    int tot = 0;
    for (int i = 0; i < N_FLT; ++i) { foffs[i] = tot; tot += fn[i]; }
    float* canon = (float*)alloc((size_t)tot * 4);
    const float* c_x    = canon + foffs[0];
    const float* c_ea   = canon + foffs[1];
    const float* c_fc1w = canon + foffs[2];
    const float* c_fc1b = canon + foffs[3];
    const float* c_k1w  = canon + foffs[4];
    const float* c_k1b  = canon + foffs[5];
    const float* c_k2w  = canon + foffs[6];
    const float* c_k2b  = canon + foffs[7];
    const float* c_k3w  = canon + foffs[8];
    const float* c_k3b  = canon + foffs[9];
    const float* c_rw   = canon + foffs[10];
    const float* c_cb   = canon + foffs[11];
    const float* c_fc2w = canon + foffs[12];
    const float* c_fc2b = canon + foffs[13];
    const float* c_fc3w = canon + foffs[14];
    const float* c_fc3b = canon + foffs[15];
    size_t fixed_end = off;

    // ---- mode selection (constant per harness -> graph-safe) ----
    const size_t sz_we = (size_t)E_PAD * 1024 * 2;   // 246 MB
    int mode, T;
    if (ws_size >= fixed_end + sz_we + 1024) { mode = 1; T = NTILES; }
    else {
        mode = 0;
        size_t per_tile = (size_t)128 * 1024 * 2;
        size_t extra = alignup((size_t)NN * 32 * 4);
        size_t avail = ws_size > fixed_end + extra + 4096
                     ? ws_size - fixed_end - extra - 4096 : per_tile;
        long t = (long)(avail / per_tile);
        if (t > NTILES) t = NTILES;
        if (t < 1) t = 1;
        T = (int)t;
    }
    bf16_t* w_e = nullptr;
    float* aggr = nullptr;
    if (mode == 1) {
        w_e = (bf16_t*)alloc(sz_we);
    } else {
        aggr = (float*)alloc((size_t)NN * 32 * 4);
        w_e  = (bf16_t*)alloc((size_t)T * 128 * 1024 * 2);
    }

    hipMemsetAsync(cnti, 0, (size_t)NN * 4, stream);
    hipMemsetAsync(f32fl, 0, 256, stream);
    hipMemsetAsync(idxfl, 0, 256, stream);

    detect_f32<<<32, 256, 0, stream>>>((const unsigned short*)d_in[2], f32fl);

    CvtArgs ca;
    for (int i = 0; i < N_FLT; ++i) {
        ca.src[i] = d_in[fidx[i]];
        ca.offs[i] = foffs[i];
        ca.n[i] = fn[i];
    }
    ca.dst = canon;
    ca.tot = tot;
    cvt_flat<<<(tot + 255) / 256, 256, 0, stream>>>(ca, f32fl);

    detect_idx<<<16, 256, 0, stream>>>(ei, idxfl);
    repack_idx<<<(EE + 255) / 256, 256, 0, stream>>>(ei, idxfl, srcb, dstb, cnti);
    scan_kernel<<<1, 256, 0, stream>>>(cnti, rowo, pos);
    scatter_rank<<<(E_PAD + 255) / 256, 256, 0, stream>>>(dstb, srcb, pos, rankb, src_s);

    transpose_bt<<<(128 * 256 + 255) / 256, 256, 0, stream>>>(c_k2w, k2t, 128, 256, 0);
    transpose_bt<<<(256 * 1024 + 255) / 256, 256, 0, stream>>>(c_k3w, k3t, 256, 1024, 1);
    permute_bias<<<4, 256, 0, stream>>>(c_k3b, k3bp);
    h0_kernel<<<NN * 32 / 256, 256, 0, stream>>>(c_x, c_fc1w, c_fc1b, h_a);

    float* hc = h_a;
    float* hn = h_b;
    if (mode == 1) {
        fused_prep<<<NTILES, 256, 0, stream>>>(c_ea, c_k1w, c_k1b, k2t, c_k2b,
                                               k3t, k3bp, w_e, rankb, 0, 1);
        for (int d = 0; d < 4; ++d) {
            gather_stream<<<(NN + 3) / 4, 256, 0, stream>>>(hc, w_e, src_s, rowo,
                                                            c_rw, c_cb, hn,
                                                            (d < 3) ? 1 : 0, d & 1);
            float* tmp = hc; hc = hn; hn = tmp;
        }
    } else {
        for (int d = 0; d < 4; ++d) {
            hipMemsetAsync(aggr, 0, (size_t)NN * 32 * 4, stream);
            for (int t0 = 0; t0 < NTILES; t0 += T) {
                int tl = (t0 + T <= NTILES) ? T : (NTILES - t0);
                fused_prep<<<tl, 256, 0, stream>>>(c_ea, c_k1w, c_k1b, k2t, c_k2b,
                                                   k3t, k3bp, w_e, rankb, t0, 0);
                int e0 = t0 * 128;
                int e1 = e0 + tl * 128; if (e1 > EE) e1 = EE;
                if (e1 > e0)
                    edge_scatter<<<(e1 - e0 + 3) / 4, 256, 0, stream>>>(hc, w_e, srcb, dstb,
                                                                        aggr, e0, e1);
            }
            node_update<<<NN * 32 / 256, 256, 0, stream>>>(hc, aggr, cnti, c_rw, c_cb, hn,
                                                           (d < 3) ? 1 : 0);
            float* tmp = hc; hc = hn; hn = tmp;
        }
    }

    head_kernel<<<(NN + 3) / 4, 256, 0, stream>>>(hc, c_fc2w, c_fc2b, c_fc3w, c_fc3b,
                                                  d_out, f32fl);
}

// Round 10
// 540.324 us; speedup vs baseline: 1.2738x; 1.1407x over previous
//
#include <hip/hip_runtime.h>
#include <hip/hip_bf16.h>

#define NN 10000
#define EE 120000
#define E_PAD 120064   // 1876 * 64
#define NT64 1876      // E_PAD / 64

#define H1S 136        // h1 LDS row stride (elems); 68 words ≡ 4 (mod 32)
#define H2S 264        // h2 LDS row stride (elems); 132 words ≡ 4 (mod 32)

typedef __bf16 bf16_t;
typedef __bf16 bf16x8 __attribute__((ext_vector_type(8)));
typedef float f32x4 __attribute__((ext_vector_type(4)));

static __device__ __forceinline__ int clampi(int v) {
    return v < 0 ? 0 : (v >= NN ? NN - 1 : v);
}

// ---- float dtype detection -------------------------------------------------
__global__ __launch_bounds__(256) void detect_f32(const unsigned short* __restrict__ ea_raw,
                                                  int* __restrict__ flag) {
    int t = blockIdx.x * 256 + threadIdx.x;
    if (ea_raw[t] & 0x8000) atomicOr(flag, 1);
}

// ---- batched convert of all 16 float tensors to canonical fp32 (flat grid) -
#define N_FLT 16
struct CvtArgs {
    const void* src[N_FLT];
    float* dst;
    int offs[N_FLT];
    int n[N_FLT];
    int tot;
};

__global__ __launch_bounds__(256) void cvt_flat(CvtArgs a, const int* __restrict__ isf32) {
    int i = blockIdx.x * 256 + threadIdx.x;
    if (i >= a.tot) return;
    int t = 0;
#pragma unroll
    for (int k = 1; k < N_FLT; ++k) if (i >= a.offs[k]) t = k;
    int il = i - a.offs[t];
    float v;
    if (*isf32) v = ((const float*)a.src[t])[il];
    else        v = (float)((const bf16_t*)a.src[t])[il];
    if (!isfinite(v)) v = 0.f;
    a.dst[i] = v;
}

// ---- index dtype handling (int32 vs int64) ---------------------------------
__global__ __launch_bounds__(256) void detect_idx(const int* __restrict__ ei,
                                                  int* __restrict__ flag) {
    int t = blockIdx.x * 256 + threadIdx.x;
    if (ei[2 * t + 1] != 0) atomicOr(flag, 1);
}

__global__ __launch_bounds__(256) void repack_idx(const int* __restrict__ ei,
                                                  const int* __restrict__ flag,
                                                  int* __restrict__ s,
                                                  int* __restrict__ d,
                                                  int* __restrict__ cnti) {
    int e = blockIdx.x * 256 + threadIdx.x;
    if (e >= EE) return;
    int sv, dv;
    if (*flag == 0) {   // int64
        sv = clampi(ei[2 * e]);
        dv = clampi(ei[2 * (EE + e)]);
    } else {            // int32
        sv = clampi(ei[e]);
        dv = clampi(ei[EE + e]);
    }
    s[e] = sv;
    d[e] = dv;
    atomicAdd(&cnti[dv], 1);
}

// single-block exclusive scan of cnti[NN] -> row_off[NN+1], pos copy
__global__ __launch_bounds__(256) void scan_kernel(const int* __restrict__ cnti,
                                                   int* __restrict__ row_off,
                                                   int* __restrict__ pos) {
    __shared__ int part[256];
    const int t = threadIdx.x;
    const int CH = (NN + 255) / 256;
    int s = 0;
    for (int i = 0; i < CH; ++i) {
        int idx = t * CH + i;
        if (idx < NN) s += cnti[idx];
    }
    part[t] = s;
    __syncthreads();
    for (int off = 1; off < 256; off <<= 1) {
        int tmp = (t >= off) ? part[t - off] : 0;
        __syncthreads();
        part[t] += tmp;
        __syncthreads();
    }
    int run = part[t] - s;
    for (int i = 0; i < CH; ++i) {
        int idx = t * CH + i;
        if (idx < NN) {
            row_off[idx] = run;
            pos[idx] = run;
            run += cnti[idx];
        }
    }
    if (t == 255) row_off[NN] = run;
}

// rank[e] = dst-sorted position of edge e; src_s[p] = src of sorted edge p
__global__ __launch_bounds__(256) void scatter_rank(const int* __restrict__ dst,
                                                    const int* __restrict__ src,
                                                    int* __restrict__ pos,
                                                    int* __restrict__ rank,
                                                    int* __restrict__ src_s) {
    int e = blockIdx.x * 256 + threadIdx.x;
    if (e >= E_PAD) return;
    if (e >= EE) { rank[e] = e; return; }
    int p = atomicAdd(&pos[dst[e]], 1);
    rank[e] = p;
    src_s[p] = src[e];
}

// ---- small prep ------------------------------------------------------------

// Bt[n][k] = B[k][n]  (permute=1: k3 output cols reordered to [out][in])
__global__ __launch_bounds__(256) void transpose_bt(const float* __restrict__ B,
                                                    bf16_t* __restrict__ Bt, int K, int N,
                                                    int permute) {
    int idx = blockIdx.x * 256 + threadIdx.x;
    if (idx >= K * N) return;
    int n = idx / K, k = idx - n * K;
    int c = permute ? (((n & 31) << 5) | (n >> 5)) : n;
    Bt[idx] = (bf16_t)B[k * N + c];
}

__global__ __launch_bounds__(256) void permute_bias(const float* __restrict__ b,
                                                    float* __restrict__ bp) {
    int n = blockIdx.x * 256 + threadIdx.x;
    bp[n] = b[((n & 31) << 5) | (n >> 5)];
}

// h0 = x @ fc1_w + fc1_b
__global__ __launch_bounds__(256) void h0_kernel(const float* __restrict__ x,
                                                 const float* __restrict__ w,
                                                 const float* __restrict__ b,
                                                 float* __restrict__ h) {
    int gid = blockIdx.x * 256 + threadIdx.x;
    int n = gid >> 5, o = gid & 31;
    float acc = b[o];
#pragma unroll
    for (int j = 0; j < 6; ++j) acc += x[n * 6 + j] * w[j * 32 + o];
    h[gid] = acc;
}

// ---- FUSED PREP v2: 64-edge tiles, ~50 KB LDS -> 3 blocks/CU ---------------
// Per tile: h1 (VALU->LDS) -> k2 (MFMA, h2->LDS) -> k3 (MFMA) -> w_e global.
// A-operands from LDS (strides 68/132 words = 2-way-free banks); B-operands
// direct from L2-hot k2t (64 KB) / k3t (512 KB). 3 barriers per block.
// Waves: 1x4 split — wave w owns a 64-col slice, all 64 M-rows.
__global__ __launch_bounds__(256) void fused_prep(const float* __restrict__ ea,
                                                  const float* __restrict__ k1w,
                                                  const float* __restrict__ k1b,
                                                  const bf16_t* __restrict__ k2t,
                                                  const float* __restrict__ k2b,
                                                  const bf16_t* __restrict__ k3t,
                                                  const float* __restrict__ k3bp,
                                                  bf16_t* __restrict__ we,
                                                  const int* __restrict__ rank,
                                                  int tile0, int perm) {
    __shared__ bf16_t h1_s[64 * H1S];   // 17408 B
    __shared__ bf16_t h2_s[64 * H2S];   // 33792 B
    // phase-0/1 staging aliased into h2_s (not yet live):
    float* ea_s  = (float*)h2_s;        // 64*6*4  = 1536 B
    float* k1w_s = ea_s + 64 * 6;       // 768*4   = 3072 B
    float* k1b_s = k1w_s + 768;         // 128*4   =  512 B

    const int t = threadIdx.x;
    const int tile = tile0 + blockIdx.x;
    const int e0 = tile * 64;

    // Phase 0: stage edge_attr tile + k1 weights
    for (int i = t; i < 384; i += 256) {
        int r = i / 6, j = i - r * 6;
        int e = e0 + r;
        ea_s[i] = (e < EE) ? ea[(size_t)e * 6 + j] : 0.f;
    }
    for (int i = t; i < 768; i += 256) k1w_s[i] = k1w[i];
    if (t < 128) k1b_s[t] = k1b[t];
    __syncthreads();

    // Phase 1: h1 = relu(ea @ k1w + k1b) -> LDS (64 x 128, stride H1S)
    {
        const int o = t & 127, rh = t >> 7;   // 32 rows each
        for (int r = rh * 32; r < rh * 32 + 32; ++r) {
            float acc = k1b_s[o];
#pragma unroll
            for (int j = 0; j < 6; ++j) acc += ea_s[r * 6 + j] * k1w_s[j * 128 + o];
            h1_s[r * H1S + o] = (bf16_t)fmaxf(acc, 0.f);
        }
    }
    __syncthreads();   // ea_s/k1w_s (aliased with h2_s) fully consumed here

    const int lane = t & 63;
    const int w = t >> 6;                 // wave -> 64-col slice
    const int nr16 = lane & 15;
    const int koff = (lane >> 4) * 8;
    const int rbase = (lane >> 4) * 4;

    // Phase 2: h2 = relu(h1 @ k2t^T + k2b) -> LDS (64 x 256, stride H2S)
    {
        f32x4 acc[4][4];
#pragma unroll
        for (int i = 0; i < 4; ++i)
#pragma unroll
            for (int j = 0; j < 4; ++j) acc[i][j] = f32x4{0.f, 0.f, 0.f, 0.f};
#pragma unroll
        for (int ks = 0; ks < 4; ++ks) {
            const int k0 = ks * 32;
            bf16x8 af[4], bfr[4];
#pragma unroll
            for (int i = 0; i < 4; ++i)
                af[i] = *(const bf16x8*)&h1_s[(nr16 + i * 16) * H1S + k0 + koff];
#pragma unroll
            for (int j = 0; j < 4; ++j)
                bfr[j] = *(const bf16x8*)&k2t[(w * 64 + j * 16 + nr16) * 128 + k0 + koff];
#pragma unroll
            for (int i = 0; i < 4; ++i)
#pragma unroll
                for (int j = 0; j < 4; ++j)
                    acc[i][j] = __builtin_amdgcn_mfma_f32_16x16x32_bf16(af[i], bfr[j], acc[i][j], 0, 0, 0);
        }
#pragma unroll
        for (int i = 0; i < 4; ++i) {
#pragma unroll
            for (int j = 0; j < 4; ++j) {
                int col = w * 64 + j * 16 + nr16;
                float bv = k2b[col];
#pragma unroll
                for (int r = 0; r < 4; ++r) {
                    int row = i * 16 + rbase + r;
                    h2_s[row * H2S + col] = (bf16_t)fmaxf(acc[i][j][r] + bv, 0.f);
                }
            }
        }
    }
    __syncthreads();

    // Phase 3: w_e_tile = h2 @ k3t^T + k3bp -> global (rank-scattered rows)
#pragma unroll 1
    for (int nt = 0; nt < 4; ++nt) {
        const int c0 = nt * 256 + w * 64;
        f32x4 acc[4][4];
#pragma unroll
        for (int i = 0; i < 4; ++i)
#pragma unroll
            for (int j = 0; j < 4; ++j) acc[i][j] = f32x4{0.f, 0.f, 0.f, 0.f};
#pragma unroll 1
        for (int ks = 0; ks < 8; ++ks) {
            const int k0 = ks * 32;
            bf16x8 af[4], bfr[4];
#pragma unroll
            for (int i = 0; i < 4; ++i)
                af[i] = *(const bf16x8*)&h2_s[(nr16 + i * 16) * H2S + k0 + koff];
#pragma unroll
            for (int j = 0; j < 4; ++j)
                bfr[j] = *(const bf16x8*)&k3t[(size_t)(c0 + j * 16 + nr16) * 256 + k0 + koff];
#pragma unroll
            for (int i = 0; i < 4; ++i)
#pragma unroll
                for (int j = 0; j < 4; ++j)
                    acc[i][j] = __builtin_amdgcn_mfma_f32_16x16x32_bf16(af[i], bfr[j], acc[i][j], 0, 0, 0);
        }
#pragma unroll
        for (int i = 0; i < 4; ++i) {
#pragma unroll
            for (int r = 0; r < 4; ++r) {
                int lr = i * 16 + rbase + r;
                long er = (long)e0 + lr;
                long crow = perm ? (long)rank[er] : (long)blockIdx.x * 64 + lr;
#pragma unroll
                for (int j = 0; j < 4; ++j) {
                    int col = c0 + j * 16 + nr16;
                    we[crow * 1024 + col] = (bf16_t)(acc[i][j][r] + k3bp[col]);
                }
            }
        }
    }
}

// ---- CSR layer, dst-sorted streaming w_e; one wave per node; no atomics ----
__global__ __launch_bounds__(256) void gather_stream(const float* __restrict__ h,
                                                     const bf16_t* __restrict__ wt,
                                                     const int* __restrict__ src_s,
                                                     const int* __restrict__ row_off,
                                                     const float* __restrict__ rw,
                                                     const float* __restrict__ cb,
                                                     float* __restrict__ hout,
                                                     int relu, int rev) {
    __shared__ float rws[1024];
    for (int i = threadIdx.x; i < 1024; i += 256) rws[i] = rw[i];
    __syncthreads();
    const int wv = threadIdx.x >> 6, lane = threadIdx.x & 63;
    const int nb = rev ? ((int)gridDim.x - 1 - blockIdx.x) : blockIdx.x;
    const int n = nb * 4 + wv;
    if (n >= NN) return;
    const int o = lane >> 1, half = lane & 1;

    const int b0 = row_off[n], b1 = row_off[n + 1];
    float acc = 0.f;
    if (b0 < b1) {
        int s = src_s[b0];
        const float4* hp = (const float4*)(h + (size_t)s * 32 + half * 16);
        float4 ha = hp[0], hb = hp[1], hcv = hp[2], hd = hp[3];
        const bf16x8* wp = (const bf16x8*)(wt + (size_t)b0 * 1024 + lane * 16);
        bf16x8 w0 = wp[0], w1 = wp[1];
        for (int k = b0; k + 1 < b1; ++k) {
            int s2 = src_s[k + 1];
            const float4* hp2 = (const float4*)(h + (size_t)s2 * 32 + half * 16);
            float4 na = hp2[0], nb2 = hp2[1], nc = hp2[2], nd = hp2[3];
            const bf16x8* wp2 = (const bf16x8*)(wt + (size_t)(k + 1) * 1024 + lane * 16);
            bf16x8 nw0 = wp2[0], nw1 = wp2[1];
            acc += ha.x * (float)w0[0] + ha.y * (float)w0[1]
                 + ha.z * (float)w0[2] + ha.w * (float)w0[3]
                 + hb.x * (float)w0[4] + hb.y * (float)w0[5]
                 + hb.z * (float)w0[6] + hb.w * (float)w0[7]
                 + hcv.x * (float)w1[0] + hcv.y * (float)w1[1]
                 + hcv.z * (float)w1[2] + hcv.w * (float)w1[3]
                 + hd.x * (float)w1[4] + hd.y * (float)w1[5]
                 + hd.z * (float)w1[6] + hd.w * (float)w1[7];
            ha = na; hb = nb2; hcv = nc; hd = nd; w0 = nw0; w1 = nw1;
        }
        acc += ha.x * (float)w0[0] + ha.y * (float)w0[1]
             + ha.z * (float)w0[2] + ha.w * (float)w0[3]
             + hb.x * (float)w0[4] + hb.y * (float)w0[5]
             + hb.z * (float)w0[6] + hb.w * (float)w0[7]
             + hcv.x * (float)w1[0] + hcv.y * (float)w1[1]
             + hcv.z * (float)w1[2] + hcv.w * (float)w1[3]
             + hd.x * (float)w1[4] + hd.y * (float)w1[5]
             + hd.z * (float)w1[6] + hd.w * (float)w1[7];
    }

    float rp = 0.f;
    const float4* hn = (const float4*)(h + (size_t)n * 32 + half * 16);
    float4 a = hn[0], b = hn[1], c = hn[2], dd = hn[3];
    const float* rwb = &rws[half * 16 * 32 + o];
    rp += a.x * rwb[0]   + a.y * rwb[32]  + a.z * rwb[64]  + a.w * rwb[96];
    rp += b.x * rwb[128] + b.y * rwb[160] + b.z * rwb[192] + b.w * rwb[224];
    rp += c.x * rwb[256] + c.y * rwb[288] + c.z * rwb[320] + c.w * rwb[352];
    rp += dd.x * rwb[384] + dd.y * rwb[416] + dd.z * rwb[448] + dd.w * rwb[480];

    acc += __shfl_xor(acc, 1, 64);
    rp  += __shfl_xor(rp, 1, 64);
    if (half == 0) {
        float den = fmaxf((float)(b1 - b0), 1.f);
        float v = acc / den + rp + cb[o];
        if (relu) v = fmaxf(v, 0.f);
        hout[(size_t)n * 32 + o] = v;
    }
}

// ---- fallback (ws too small for full w_e): per-edge wave + atomics ---------
__global__ __launch_bounds__(256) void edge_scatter(const float* __restrict__ h,
                                                    const bf16_t* __restrict__ wt,
                                                    const int* __restrict__ src,
                                                    const int* __restrict__ dst,
                                                    float* __restrict__ aggr,
                                                    int e0, int e1) {
    int wv = threadIdx.x >> 6, lane = threadIdx.x & 63;
    int e = e0 + blockIdx.x * 4 + wv;
    if (e >= e1) return;
    int s = src[e], d = dst[e];
    int o = lane & 31, ihalf = lane >> 5;
    const float4* hp = (const float4*)(h + (size_t)s * 32 + ihalf * 16);
    float4 ha = hp[0], hb = hp[1], hcv = hp[2], hd = hp[3];
    const bf16x8* wp = (const bf16x8*)(wt + (size_t)(e - e0) * 1024 + o * 32 + ihalf * 16);
    bf16x8 w0 = wp[0], w1 = wp[1];
    float acc = ha.x * (float)w0[0] + ha.y * (float)w0[1]
              + ha.z * (float)w0[2] + ha.w * (float)w0[3]
              + hb.x * (float)w0[4] + hb.y * (float)w0[5]
              + hb.z * (float)w0[6] + hb.w * (float)w0[7]
              + hcv.x * (float)w1[0] + hcv.y * (float)w1[1]
              + hcv.z * (float)w1[2] + hcv.w * (float)w1[3]
              + hd.x * (float)w1[4] + hd.y * (float)w1[5]
              + hd.z * (float)w1[6] + hd.w * (float)w1[7];
    acc += __shfl_xor(acc, 32, 64);
    if (ihalf == 0) atomicAdd(&aggr[(size_t)d * 32 + o], acc);
}

__global__ __launch_bounds__(256) void node_update(const float* __restrict__ hin,
                                                   const float* __restrict__ aggr,
                                                   const int* __restrict__ cnti,
                                                   const float* __restrict__ rw,
                                                   const float* __restrict__ cb,
                                                   float* __restrict__ hout, int relu) {
    __shared__ float rws[32 * 32];
    for (int i = threadIdx.x; i < 1024; i += 256) rws[i] = rw[i];
    __syncthreads();
    int gid = blockIdx.x * 256 + threadIdx.x;
    int n = gid >> 5, o = gid & 31;
    float den = fmaxf((float)cnti[n], 1.f);
    float acc = aggr[gid] / den + cb[o];
    const float* hrow = hin + (size_t)n * 32;
#pragma unroll
    for (int j = 0; j < 32; ++j) acc += hrow[j] * rws[j * 32 + o];
    if (relu) acc = fmaxf(acc, 0.f);
    hout[gid] = acc;
}

// out = relu(h @ fc2 + b2) @ fc3 + b3
__global__ __launch_bounds__(256) void head_kernel(const float* __restrict__ h,
                                                   const float* __restrict__ w2,
                                                   const float* __restrict__ b2,
                                                   const float* __restrict__ w3,
                                                   const float* __restrict__ b3,
                                                   void* __restrict__ out,
                                                   const int* __restrict__ isf32) {
    int wave = threadIdx.x >> 6, lane = threadIdx.x & 63;
    int n = blockIdx.x * 4 + wave;
    if (n >= NN) return;
    const float* hrow = h + (size_t)n * 32;
    float hr[32];
#pragma unroll
    for (int j = 0; j < 32; ++j) hr[j] = hrow[j];
    int o0 = lane * 2, o1 = lane * 2 + 1;
    float v0 = b2[o0], v1 = b2[o1];
#pragma unroll
    for (int j = 0; j < 32; ++j) {
        float hj = hr[j];
        v0 += hj * w2[j * 128 + o0];
        v1 += hj * w2[j * 128 + o1];
    }
    float y = fmaxf(v0, 0.f) * w3[o0] + fmaxf(v1, 0.f) * w3[o1];
#pragma unroll
    for (int m = 1; m < 64; m <<= 1) y += __shfl_xor(y, m, 64);
    if (lane == 0) {
        float r = y + b3[0];
        if (*isf32) ((float*)out)[n] = r;
        else        ((bf16_t*)out)[n] = (bf16_t)r;
    }
}

// ---------------------------------------------------------------------------

extern "C" void kernel_launch(void* const* d_in, const int* in_sizes, int n_in,
                              void* d_out, int out_size, void* d_ws, size_t ws_size,
                              hipStream_t stream) {
    const int* ei = (const int*)d_in[1];

    char* ws = (char*)d_ws;
    size_t off = 0;
    auto alignup = [](size_t b) { return (b + 255) & ~(size_t)255; };
    auto alloc = [&](size_t bytes) {
        char* p = ws + off;
        off += alignup(bytes);
        return (void*)p;
    };
    float*  h_a   = (float*)alloc((size_t)NN * 32 * 4);
    float*  h_b   = (float*)alloc((size_t)NN * 32 * 4);
    int*    cnti  = (int*)alloc((size_t)NN * 4);
    int*    rowo  = (int*)alloc((size_t)(NN + 1) * 4);
    int*    pos   = (int*)alloc((size_t)NN * 4);
    int*    f32fl = (int*)alloc(256);
    int*    idxfl = (int*)alloc(256);
    int*    srcb  = (int*)alloc((size_t)EE * 4);
    int*    dstb  = (int*)alloc((size_t)EE * 4);
    int*    rankb = (int*)alloc((size_t)E_PAD * 4);
    int*    src_s = (int*)alloc((size_t)E_PAD * 4);
    bf16_t* k2t   = (bf16_t*)alloc(256 * 128 * 2);
    bf16_t* k3t   = (bf16_t*)alloc(1024 * 256 * 2);
    float*  k3bp  = (float*)alloc(1024 * 4);

    static const int fidx[N_FLT] = {0, 2, 3, 4, 5, 6, 7, 8, 9, 10, 11, 12, 13, 14, 15, 16};
    static const int fn[N_FLT]   = {NN * 6, EE * 6, 192, 32, 768, 128, 32768, 256,
                                    262144, 1024, 1024, 32, 4096, 128, 128, 1};
    int foffs[N_FLT];
    int tot = 0;
    for (int i = 0; i < N_FLT; ++i) { foffs[i] = tot; tot += fn[i]; }
    float* canon = (float*)alloc((size_t)tot * 4);
    const float* c_x    = canon + foffs[0];
    const float* c_ea   = canon + foffs[1];
    const float* c_fc1w = canon + foffs[2];
    const float* c_fc1b = canon + foffs[3];
    const float* c_k1w  = canon + foffs[4];
    const float* c_k1b  = canon + foffs[5];
    const float* c_k2w  = canon + foffs[6];
    const float* c_k2b  = canon + foffs[7];
    const float* c_k3w  = canon + foffs[8];
    const float* c_k3b  = canon + foffs[9];
    const float* c_rw   = canon + foffs[10];
    const float* c_cb   = canon + foffs[11];
    const float* c_fc2w = canon + foffs[12];
    const float* c_fc2b = canon + foffs[13];
    const float* c_fc3w = canon + foffs[14];
    const float* c_fc3b = canon + foffs[15];
    size_t fixed_end = off;

    // ---- mode selection (constant per harness -> graph-safe) ----
    const size_t sz_we = (size_t)E_PAD * 1024 * 2;   // 246 MB
    int mode, T;
    if (ws_size >= fixed_end + sz_we + 1024) { mode = 1; T = NT64; }
    else {
        mode = 0;
        size_t per_tile = (size_t)64 * 1024 * 2;
        size_t extra = alignup((size_t)NN * 32 * 4);
        size_t avail = ws_size > fixed_end + extra + 4096
                     ? ws_size - fixed_end - extra - 4096 : per_tile;
        long t = (long)(avail / per_tile);
        if (t > NT64) t = NT64;
        if (t < 1) t = 1;
        T = (int)t;
    }
    bf16_t* w_e = nullptr;
    float* aggr = nullptr;
    if (mode == 1) {
        w_e = (bf16_t*)alloc(sz_we);
    } else {
        aggr = (float*)alloc((size_t)NN * 32 * 4);
        w_e  = (bf16_t*)alloc((size_t)T * 64 * 1024 * 2);
    }

    hipMemsetAsync(cnti, 0, (size_t)NN * 4, stream);
    hipMemsetAsync(f32fl, 0, 256, stream);
    hipMemsetAsync(idxfl, 0, 256, stream);

    detect_f32<<<32, 256, 0, stream>>>((const unsigned short*)d_in[2], f32fl);

    CvtArgs ca;
    for (int i = 0; i < N_FLT; ++i) {
        ca.src[i] = d_in[fidx[i]];
        ca.offs[i] = foffs[i];
        ca.n[i] = fn[i];
    }
    ca.dst = canon;
    ca.tot = tot;
    cvt_flat<<<(tot + 255) / 256, 256, 0, stream>>>(ca, f32fl);

    detect_idx<<<16, 256, 0, stream>>>(ei, idxfl);
    repack_idx<<<(EE + 255) / 256, 256, 0, stream>>>(ei, idxfl, srcb, dstb, cnti);
    scan_kernel<<<1, 256, 0, stream>>>(cnti, rowo, pos);
    scatter_rank<<<(E_PAD + 255) / 256, 256, 0, stream>>>(dstb, srcb, pos, rankb, src_s);

    transpose_bt<<<(128 * 256 + 255) / 256, 256, 0, stream>>>(c_k2w, k2t, 128, 256, 0);
    transpose_bt<<<(256 * 1024 + 255) / 256, 256, 0, stream>>>(c_k3w, k3t, 256, 1024, 1);
    permute_bias<<<4, 256, 0, stream>>>(c_k3b, k3bp);
    h0_kernel<<<NN * 32 / 256, 256, 0, stream>>>(c_x, c_fc1w, c_fc1b, h_a);

    float* hc = h_a;
    float* hn = h_b;
    if (mode == 1) {
        fused_prep<<<NT64, 256, 0, stream>>>(c_ea, c_k1w, c_k1b, k2t, c_k2b,
                                             k3t, k3bp, w_e, rankb, 0, 1);
        for (int d = 0; d < 4; ++d) {
            gather_stream<<<(NN + 3) / 4, 256, 0, stream>>>(hc, w_e, src_s, rowo,
                                                            c_rw, c_cb, hn,
                                                            (d < 3) ? 1 : 0, d & 1);
            float* tmp = hc; hc = hn; hn = tmp;
        }
    } else {
        for (int d = 0; d < 4; ++d) {
            hipMemsetAsync(aggr, 0, (size_t)NN * 32 * 4, stream);
            for (int t0 = 0; t0 < NT64; t0 += T) {
                int tl = (t0 + T <= NT64) ? T : (NT64 - t0);
                fused_prep<<<tl, 256, 0, stream>>>(c_ea, c_k1w, c_k1b, k2t, c_k2b,
                                                   k3t, k3bp, w_e, rankb, t0, 0);
                int e0 = t0 * 64;
                int e1 = e0 + tl * 64; if (e1 > EE) e1 = EE;
                if (e1 > e0)
                    edge_scatter<<<(e1 - e0 + 3) / 4, 256, 0, stream>>>(hc, w_e, srcb, dstb,
                                                                        aggr, e0, e1);
            }
            node_update<<<NN * 32 / 256, 256, 0, stream>>>(hc, aggr, cnti, c_rw, c_cb, hn,
                                                           (d < 3) ? 1 : 0);
            float* tmp = hc; hc = hn; hn = tmp;
        }
    }

    head_kernel<<<(NN + 3) / 4, 256, 0, stream>>>(hc, c_fc2w, c_fc2b, c_fc3w, c_fc3b,
                                                  d_out, f32fl);
}

// Round 11
// 492.707 us; speedup vs baseline: 1.3969x; 1.0966x over previous
//
#include <hip/hip_runtime.h>
#include <hip/hip_bf16.h>

#define NN 10000
#define EE 120000
#define E_PAD 120064   // 1876 * 64
#define NT64 1876      // E_PAD / 64

#define H1S 136        // h1 LDS row stride (elems); 68 words ≡ 4 (mod 32)
#define H2S 264        // h2 LDS row stride (elems); 132 words ≡ 4 (mod 32)

typedef __bf16 bf16_t;
typedef __bf16 bf16x8 __attribute__((ext_vector_type(8)));
typedef float f32x4 __attribute__((ext_vector_type(4)));

static __device__ __forceinline__ int clampi(int v) {
    return v < 0 ? 0 : (v >= NN ? NN - 1 : v);
}

// ---- combined dtype detection (float + index) ------------------------------
__global__ __launch_bounds__(256) void detect_all(const unsigned short* __restrict__ ea_raw,
                                                  const int* __restrict__ ei,
                                                  int* __restrict__ f32fl,
                                                  int* __restrict__ idxfl) {
    int t = blockIdx.x * 256 + threadIdx.x;          // [0, 8192)
    if (ea_raw[t] & 0x8000) atomicOr(f32fl, 1);      // fp32 low-words have bit15 set ~50%
    if (t < 4096 && ei[2 * t + 1] != 0) atomicOr(idxfl, 1);
}

// ---- batched convert of all 16 float tensors to canonical fp32 (flat grid) -
#define N_FLT 16
struct CvtArgs {
    const void* src[N_FLT];
    float* dst;
    int offs[N_FLT];
    int n[N_FLT];
    int tot;
};

__global__ __launch_bounds__(256) void cvt_flat(CvtArgs a, const int* __restrict__ isf32) {
    int i = blockIdx.x * 256 + threadIdx.x;
    if (i >= a.tot) return;
    int t = 0;
#pragma unroll
    for (int k = 1; k < N_FLT; ++k) if (i >= a.offs[k]) t = k;
    int il = i - a.offs[t];
    float v;
    if (*isf32) v = ((const float*)a.src[t])[il];
    else        v = (float)((const bf16_t*)a.src[t])[il];
    if (!isfinite(v)) v = 0.f;
    a.dst[i] = v;
}

__global__ __launch_bounds__(256) void repack_idx(const int* __restrict__ ei,
                                                  const int* __restrict__ flag,
                                                  int* __restrict__ s,
                                                  int* __restrict__ d,
                                                  int* __restrict__ cnti) {
    int e = blockIdx.x * 256 + threadIdx.x;
    if (e >= EE) return;
    int sv, dv;
    if (*flag == 0) {   // int64
        sv = clampi(ei[2 * e]);
        dv = clampi(ei[2 * (EE + e)]);
    } else {            // int32
        sv = clampi(ei[e]);
        dv = clampi(ei[EE + e]);
    }
    s[e] = sv;
    d[e] = dv;
    atomicAdd(&cnti[dv], 1);
}

// single-block exclusive scan of cnti[NN] -> row_off[NN+1], pos copy
__global__ __launch_bounds__(256) void scan_kernel(const int* __restrict__ cnti,
                                                   int* __restrict__ row_off,
                                                   int* __restrict__ pos) {
    __shared__ int part[256];
    const int t = threadIdx.x;
    const int CH = (NN + 255) / 256;
    int s = 0;
    for (int i = 0; i < CH; ++i) {
        int idx = t * CH + i;
        if (idx < NN) s += cnti[idx];
    }
    part[t] = s;
    __syncthreads();
    for (int off = 1; off < 256; off <<= 1) {
        int tmp = (t >= off) ? part[t - off] : 0;
        __syncthreads();
        part[t] += tmp;
        __syncthreads();
    }
    int run = part[t] - s;
    for (int i = 0; i < CH; ++i) {
        int idx = t * CH + i;
        if (idx < NN) {
            row_off[idx] = run;
            pos[idx] = run;
            run += cnti[idx];
        }
    }
    if (t == 255) row_off[NN] = run;
}

// rank[e] = dst-sorted position of edge e; src_s[p] = src of sorted edge p
__global__ __launch_bounds__(256) void scatter_rank(const int* __restrict__ dst,
                                                    const int* __restrict__ src,
                                                    int* __restrict__ pos,
                                                    int* __restrict__ rank,
                                                    int* __restrict__ src_s) {
    int e = blockIdx.x * 256 + threadIdx.x;
    if (e >= E_PAD) return;
    if (e >= EE) { rank[e] = e; return; }
    int p = atomicAdd(&pos[dst[e]], 1);
    rank[e] = p;
    src_s[p] = src[e];
}

// ---- fused small prep: k2 transpose | k3 transpose+permute | k3 bias | h0 --
// segments: [0,32768) k2t ; [32768,294912) k3t ; [294912,295936) k3bp ;
//           [295936,615936) h0
__global__ __launch_bounds__(256) void misc_prep(const float* __restrict__ k2w,
                                                 bf16_t* __restrict__ k2t,
                                                 const float* __restrict__ k3w,
                                                 bf16_t* __restrict__ k3t,
                                                 const float* __restrict__ k3b,
                                                 float* __restrict__ k3bp,
                                                 const float* __restrict__ x,
                                                 const float* __restrict__ fc1w,
                                                 const float* __restrict__ fc1b,
                                                 float* __restrict__ h0) {
    int i = blockIdx.x * 256 + threadIdx.x;
    if (i < 32768) {                       // k2t[n*128+k] = k2w[k*256+n]
        int n = i >> 7, k = i & 127;
        k2t[i] = (bf16_t)k2w[k * 256 + n];
    } else if (i < 294912) {               // k3t[n*256+k] = k3w[k*1024+perm(n)]
        int idx = i - 32768;
        int n = idx >> 8, k = idx & 255;
        int c = ((n & 31) << 5) | (n >> 5);
        k3t[idx] = (bf16_t)k3w[k * 1024 + c];
    } else if (i < 295936) {               // k3bp
        int n = i - 294912;
        k3bp[n] = k3b[((n & 31) << 5) | (n >> 5)];
    } else if (i < 615936) {               // h0 = x @ fc1_w + fc1_b
        int gid = i - 295936;
        int n = gid >> 5, o = gid & 31;
        float acc = fc1b[o];
#pragma unroll
        for (int j = 0; j < 6; ++j) acc += x[n * 6 + j] * fc1w[j * 32 + o];
        h0[gid] = acc;
    }
}

// ---- FUSED PREP v3: 64-edge tiles, 50 KB LDS, 3 blocks/CU, B-prefetch ------
// h1 (VALU->LDS) -> k2 (MFMA, h2->LDS) -> k3 (MFMA) -> w_e global.
// B operands from L2-hot k2t/k3t with manual 1-deep prefetch: next K-step's
// 4 loads issued before current step's MFMAs -> s_waitcnt vmcnt(4), loads
// stay in flight across the MFMA pack (m97/AITER lesson: never drain).
__global__ __launch_bounds__(256, 3) void fused_prep(const float* __restrict__ ea,
                                                     const float* __restrict__ k1w,
                                                     const float* __restrict__ k1b,
                                                     const bf16_t* __restrict__ k2t,
                                                     const float* __restrict__ k2b,
                                                     const bf16_t* __restrict__ k3t,
                                                     const float* __restrict__ k3bp,
                                                     bf16_t* __restrict__ we,
                                                     const int* __restrict__ rank,
                                                     int tile0, int perm) {
    __shared__ bf16_t h1_s[64 * H1S];   // 17408 B
    __shared__ bf16_t h2_s[64 * H2S];   // 33792 B
    // phase-0/1 staging aliased into h2_s (not yet live):
    float* ea_s  = (float*)h2_s;
    float* k1w_s = ea_s + 64 * 6;
    float* k1b_s = k1w_s + 768;

    const int t = threadIdx.x;
    const int tile = tile0 + blockIdx.x;
    const int e0 = tile * 64;

    // Phase 0: stage edge_attr tile + k1 weights
    for (int i = t; i < 384; i += 256) {
        int r = i / 6, j = i - r * 6;
        int e = e0 + r;
        ea_s[i] = (e < EE) ? ea[(size_t)e * 6 + j] : 0.f;
    }
    for (int i = t; i < 768; i += 256) k1w_s[i] = k1w[i];
    if (t < 128) k1b_s[t] = k1b[t];
    __syncthreads();

    // Phase 1: h1 = relu(ea @ k1w + k1b) -> LDS
    {
        const int o = t & 127, rh = t >> 7;
        for (int r = rh * 32; r < rh * 32 + 32; ++r) {
            float acc = k1b_s[o];
#pragma unroll
            for (int j = 0; j < 6; ++j) acc += ea_s[r * 6 + j] * k1w_s[j * 128 + o];
            h1_s[r * H1S + o] = (bf16_t)fmaxf(acc, 0.f);
        }
    }
    __syncthreads();   // ea_s/k1w_s (aliased with h2_s) fully consumed

    const int lane = t & 63;
    const int w = t >> 6;                 // wave -> 64-col slice
    const int nr16 = lane & 15;
    const int koff = (lane >> 4) * 8;
    const int rbase = (lane >> 4) * 4;

    // Phase 2: h2 = relu(h1 @ k2t^T + k2b) -> LDS  (pipelined B)
    {
        f32x4 acc[4][4];
#pragma unroll
        for (int i = 0; i < 4; ++i)
#pragma unroll
            for (int j = 0; j < 4; ++j) acc[i][j] = f32x4{0.f, 0.f, 0.f, 0.f};
        bf16x8 bcur[4], bnxt[4];
#pragma unroll
        for (int j = 0; j < 4; ++j)
            bcur[j] = *(const bf16x8*)&k2t[(w * 64 + j * 16 + nr16) * 128 + koff];
#pragma unroll 1
        for (int ks = 0; ks < 4; ++ks) {
            const int k0 = ks * 32;
            if (ks < 3) {
#pragma unroll
                for (int j = 0; j < 4; ++j)
                    bnxt[j] = *(const bf16x8*)&k2t[(w * 64 + j * 16 + nr16) * 128 + k0 + 32 + koff];
            }
            bf16x8 af[4];
#pragma unroll
            for (int i = 0; i < 4; ++i)
                af[i] = *(const bf16x8*)&h1_s[(nr16 + i * 16) * H1S + k0 + koff];
#pragma unroll
            for (int i = 0; i < 4; ++i)
#pragma unroll
                for (int j = 0; j < 4; ++j)
                    acc[i][j] = __builtin_amdgcn_mfma_f32_16x16x32_bf16(af[i], bcur[j], acc[i][j], 0, 0, 0);
#pragma unroll
            for (int j = 0; j < 4; ++j) bcur[j] = bnxt[j];
        }
#pragma unroll
        for (int i = 0; i < 4; ++i) {
#pragma unroll
            for (int j = 0; j < 4; ++j) {
                int col = w * 64 + j * 16 + nr16;
                float bv = k2b[col];
#pragma unroll
                for (int r = 0; r < 4; ++r) {
                    int row = i * 16 + rbase + r;
                    h2_s[row * H2S + col] = (bf16_t)fmaxf(acc[i][j][r] + bv, 0.f);
                }
            }
        }
    }
    __syncthreads();

    // hoisted output rows (16 rank lookups, issued once)
    int crow[4][4];
#pragma unroll
    for (int i = 0; i < 4; ++i)
#pragma unroll
        for (int r = 0; r < 4; ++r) {
            int lr = i * 16 + rbase + r;
            crow[i][r] = perm ? rank[e0 + lr] : (int)blockIdx.x * 64 + lr;
        }

    // Phase 3: w_e_tile = h2 @ k3t^T + k3bp -> global  (pipelined B)
#pragma unroll 1
    for (int nt = 0; nt < 4; ++nt) {
        const int c0 = nt * 256 + w * 64;
        float bj[4];
#pragma unroll
        for (int j = 0; j < 4; ++j) bj[j] = k3bp[c0 + j * 16 + nr16];
        f32x4 acc[4][4];
#pragma unroll
        for (int i = 0; i < 4; ++i)
#pragma unroll
            for (int j = 0; j < 4; ++j) acc[i][j] = f32x4{0.f, 0.f, 0.f, 0.f};
        bf16x8 bcur[4], bnxt[4];
#pragma unroll
        for (int j = 0; j < 4; ++j)
            bcur[j] = *(const bf16x8*)&k3t[(size_t)(c0 + j * 16 + nr16) * 256 + koff];
#pragma unroll 1
        for (int ks = 0; ks < 8; ++ks) {
            const int k0 = ks * 32;
            if (ks < 7) {
#pragma unroll
                for (int j = 0; j < 4; ++j)
                    bnxt[j] = *(const bf16x8*)&k3t[(size_t)(c0 + j * 16 + nr16) * 256 + k0 + 32 + koff];
            }
            bf16x8 af[4];
#pragma unroll
            for (int i = 0; i < 4; ++i)
                af[i] = *(const bf16x8*)&h2_s[(nr16 + i * 16) * H2S + k0 + koff];
#pragma unroll
            for (int i = 0; i < 4; ++i)
#pragma unroll
                for (int j = 0; j < 4; ++j)
                    acc[i][j] = __builtin_amdgcn_mfma_f32_16x16x32_bf16(af[i], bcur[j], acc[i][j], 0, 0, 0);
#pragma unroll
            for (int j = 0; j < 4; ++j) bcur[j] = bnxt[j];
        }
#pragma unroll
        for (int i = 0; i < 4; ++i) {
#pragma unroll
            for (int r = 0; r < 4; ++r) {
                long cr = crow[i][r];
#pragma unroll
                for (int j = 0; j < 4; ++j) {
                    int col = c0 + j * 16 + nr16;
                    we[cr * 1024 + col] = (bf16_t)(acc[i][j][r] + bj[j]);
                }
            }
        }
    }
}

// ---- CSR layer, dst-sorted streaming w_e; one wave per node; no atomics ----
__global__ __launch_bounds__(256) void gather_stream(const float* __restrict__ h,
                                                     const bf16_t* __restrict__ wt,
                                                     const int* __restrict__ src_s,
                                                     const int* __restrict__ row_off,
                                                     const float* __restrict__ rw,
                                                     const float* __restrict__ cb,
                                                     float* __restrict__ hout,
                                                     int relu, int rev) {
    __shared__ float rws[1024];
    for (int i = threadIdx.x; i < 1024; i += 256) rws[i] = rw[i];
    __syncthreads();
    const int wv = threadIdx.x >> 6, lane = threadIdx.x & 63;
    const int nb = rev ? ((int)gridDim.x - 1 - blockIdx.x) : blockIdx.x;
    const int n = nb * 4 + wv;
    if (n >= NN) return;
    const int o = lane >> 1, half = lane & 1;

    const int b0 = row_off[n], b1 = row_off[n + 1];
    float acc = 0.f;
    if (b0 < b1) {
        int s = src_s[b0];
        const float4* hp = (const float4*)(h + (size_t)s * 32 + half * 16);
        float4 ha = hp[0], hb = hp[1], hcv = hp[2], hd = hp[3];
        const bf16x8* wp = (const bf16x8*)(wt + (size_t)b0 * 1024 + lane * 16);
        bf16x8 w0 = wp[0], w1 = wp[1];
        for (int k = b0; k + 1 < b1; ++k) {
            int s2 = src_s[k + 1];
            const float4* hp2 = (const float4*)(h + (size_t)s2 * 32 + half * 16);
            float4 na = hp2[0], nb2 = hp2[1], nc = hp2[2], nd = hp2[3];
            const bf16x8* wp2 = (const bf16x8*)(wt + (size_t)(k + 1) * 1024 + lane * 16);
            bf16x8 nw0 = wp2[0], nw1 = wp2[1];
            acc += ha.x * (float)w0[0] + ha.y * (float)w0[1]
                 + ha.z * (float)w0[2] + ha.w * (float)w0[3]
                 + hb.x * (float)w0[4] + hb.y * (float)w0[5]
                 + hb.z * (float)w0[6] + hb.w * (float)w0[7]
                 + hcv.x * (float)w1[0] + hcv.y * (float)w1[1]
                 + hcv.z * (float)w1[2] + hcv.w * (float)w1[3]
                 + hd.x * (float)w1[4] + hd.y * (float)w1[5]
                 + hd.z * (float)w1[6] + hd.w * (float)w1[7];
            ha = na; hb = nb2; hcv = nc; hd = nd; w0 = nw0; w1 = nw1;
        }
        acc += ha.x * (float)w0[0] + ha.y * (float)w0[1]
             + ha.z * (float)w0[2] + ha.w * (float)w0[3]
             + hb.x * (float)w0[4] + hb.y * (float)w0[5]
             + hb.z * (float)w0[6] + hb.w * (float)w0[7]
             + hcv.x * (float)w1[0] + hcv.y * (float)w1[1]
             + hcv.z * (float)w1[2] + hcv.w * (float)w1[3]
             + hd.x * (float)w1[4] + hd.y * (float)w1[5]
             + hd.z * (float)w1[6] + hd.w * (float)w1[7];
    }

    float rp = 0.f;
    const float4* hn = (const float4*)(h + (size_t)n * 32 + half * 16);
    float4 a = hn[0], b = hn[1], c = hn[2], dd = hn[3];
    const float* rwb = &rws[half * 16 * 32 + o];
    rp += a.x * rwb[0]   + a.y * rwb[32]  + a.z * rwb[64]  + a.w * rwb[96];
    rp += b.x * rwb[128] + b.y * rwb[160] + b.z * rwb[192] + b.w * rwb[224];
    rp += c.x * rwb[256] + c.y * rwb[288] + c.z * rwb[320] + c.w * rwb[352];
    rp += dd.x * rwb[384] + dd.y * rwb[416] + dd.z * rwb[448] + dd.w * rwb[480];

    acc += __shfl_xor(acc, 1, 64);
    rp  += __shfl_xor(rp, 1, 64);
    if (half == 0) {
        float den = fmaxf((float)(b1 - b0), 1.f);
        float v = acc / den + rp + cb[o];
        if (relu) v = fmaxf(v, 0.f);
        hout[(size_t)n * 32 + o] = v;
    }
}

// ---- fallback (ws too small for full w_e): per-edge wave + atomics ---------
__global__ __launch_bounds__(256) void edge_scatter(const float* __restrict__ h,
                                                    const bf16_t* __restrict__ wt,
                                                    const int* __restrict__ src,
                                                    const int* __restrict__ dst,
                                                    float* __restrict__ aggr,
                                                    int e0, int e1) {
    int wv = threadIdx.x >> 6, lane = threadIdx.x & 63;
    int e = e0 + blockIdx.x * 4 + wv;
    if (e >= e1) return;
    int s = src[e], d = dst[e];
    int o = lane & 31, ihalf = lane >> 5;
    const float4* hp = (const float4*)(h + (size_t)s * 32 + ihalf * 16);
    float4 ha = hp[0], hb = hp[1], hcv = hp[2], hd = hp[3];
    const bf16x8* wp = (const bf16x8*)(wt + (size_t)(e - e0) * 1024 + o * 32 + ihalf * 16);
    bf16x8 w0 = wp[0], w1 = wp[1];
    float acc = ha.x * (float)w0[0] + ha.y * (float)w0[1]
              + ha.z * (float)w0[2] + ha.w * (float)w0[3]
              + hb.x * (float)w0[4] + hb.y * (float)w0[5]
              + hb.z * (float)w0[6] + hb.w * (float)w0[7]
              + hcv.x * (float)w1[0] + hcv.y * (float)w1[1]
              + hcv.z * (float)w1[2] + hcv.w * (float)w1[3]
              + hd.x * (float)w1[4] + hd.y * (float)w1[5]
              + hd.z * (float)w1[6] + hd.w * (float)w1[7];
    acc += __shfl_xor(acc, 32, 64);
    if (ihalf == 0) atomicAdd(&aggr[(size_t)d * 32 + o], acc);
}

__global__ __launch_bounds__(256) void node_update(const float* __restrict__ hin,
                                                   const float* __restrict__ aggr,
                                                   const int* __restrict__ cnti,
                                                   const float* __restrict__ rw,
                                                   const float* __restrict__ cb,
                                                   float* __restrict__ hout, int relu) {
    __shared__ float rws[32 * 32];
    for (int i = threadIdx.x; i < 1024; i += 256) rws[i] = rw[i];
    __syncthreads();
    int gid = blockIdx.x * 256 + threadIdx.x;
    int n = gid >> 5, o = gid & 31;
    float den = fmaxf((float)cnti[n], 1.f);
    float acc = aggr[gid] / den + cb[o];
    const float* hrow = hin + (size_t)n * 32;
#pragma unroll
    for (int j = 0; j < 32; ++j) acc += hrow[j] * rws[j * 32 + o];
    if (relu) acc = fmaxf(acc, 0.f);
    hout[gid] = acc;
}

// out = relu(h @ fc2 + b2) @ fc3 + b3
__global__ __launch_bounds__(256) void head_kernel(const float* __restrict__ h,
                                                   const float* __restrict__ w2,
                                                   const float* __restrict__ b2,
                                                   const float* __restrict__ w3,
                                                   const float* __restrict__ b3,
                                                   void* __restrict__ out,
                                                   const int* __restrict__ isf32) {
    int wave = threadIdx.x >> 6, lane = threadIdx.x & 63;
    int n = blockIdx.x * 4 + wave;
    if (n >= NN) return;
    const float* hrow = h + (size_t)n * 32;
    float hr[32];
#pragma unroll
    for (int j = 0; j < 32; ++j) hr[j] = hrow[j];
    int o0 = lane * 2, o1 = lane * 2 + 1;
    float v0 = b2[o0], v1 = b2[o1];
#pragma unroll
    for (int j = 0; j < 32; ++j) {
        float hj = hr[j];
        v0 += hj * w2[j * 128 + o0];
        v1 += hj * w2[j * 128 + o1];
    }
    float y = fmaxf(v0, 0.f) * w3[o0] + fmaxf(v1, 0.f) * w3[o1];
#pragma unroll
    for (int m = 1; m < 64; m <<= 1) y += __shfl_xor(y, m, 64);
    if (lane == 0) {
        float r = y + b3[0];
        if (*isf32) ((float*)out)[n] = r;
        else        ((bf16_t*)out)[n] = (bf16_t)r;
    }
}

// ---------------------------------------------------------------------------

extern "C" void kernel_launch(void* const* d_in, const int* in_sizes, int n_in,
                              void* d_out, int out_size, void* d_ws, size_t ws_size,
                              hipStream_t stream) {
    const int* ei = (const int*)d_in[1];

    char* ws = (char*)d_ws;
    size_t off = 0;
    auto alignup = [](size_t b) { return (b + 255) & ~(size_t)255; };
    auto alloc = [&](size_t bytes) {
        char* p = ws + off;
        off += alignup(bytes);
        return (void*)p;
    };
    float*  h_a   = (float*)alloc((size_t)NN * 32 * 4);
    float*  h_b   = (float*)alloc((size_t)NN * 32 * 4);
    // zero-block: cnti + flags in one contiguous memset region
    char*   zbase = ws + off;
    int*    cnti  = (int*)alloc((size_t)NN * 4);
    int*    f32fl = (int*)alloc(256);
    int*    idxfl = (int*)alloc(256);
    size_t  zlen  = (ws + off) - zbase;
    int*    rowo  = (int*)alloc((size_t)(NN + 1) * 4);
    int*    pos   = (int*)alloc((size_t)NN * 4);
    int*    srcb  = (int*)alloc((size_t)EE * 4);
    int*    dstb  = (int*)alloc((size_t)EE * 4);
    int*    rankb = (int*)alloc((size_t)E_PAD * 4);
    int*    src_s = (int*)alloc((size_t)E_PAD * 4);
    bf16_t* k2t   = (bf16_t*)alloc(256 * 128 * 2);
    bf16_t* k3t   = (bf16_t*)alloc(1024 * 256 * 2);
    float*  k3bp  = (float*)alloc(1024 * 4);

    static const int fidx[N_FLT] = {0, 2, 3, 4, 5, 6, 7, 8, 9, 10, 11, 12, 13, 14, 15, 16};
    static const int fn[N_FLT]   = {NN * 6, EE * 6, 192, 32, 768, 128, 32768, 256,
                                    262144, 1024, 1024, 32, 4096, 128, 128, 1};
    int foffs[N_FLT];
    int tot = 0;
    for (int i = 0; i < N_FLT; ++i) { foffs[i] = tot; tot += fn[i]; }
    float* canon = (float*)alloc((size_t)tot * 4);
    const float* c_x    = canon + foffs[0];
    const float* c_ea   = canon + foffs[1];
    const float* c_fc1w = canon + foffs[2];
    const float* c_fc1b = canon + foffs[3];
    const float* c_k1w  = canon + foffs[4];
    const float* c_k1b  = canon + foffs[5];
    const float* c_k2w  = canon + foffs[6];
    const float* c_k2b  = canon + foffs[7];
    const float* c_k3w  = canon + foffs[8];
    const float* c_k3b  = canon + foffs[9];
    const float* c_rw   = canon + foffs[10];
    const float* c_cb   = canon + foffs[11];
    const float* c_fc2w = canon + foffs[12];
    const float* c_fc2b = canon + foffs[13];
    const float* c_fc3w = canon + foffs[14];
    const float* c_fc3b = canon + foffs[15];
    size_t fixed_end = off;

    // ---- mode selection (constant per harness -> graph-safe) ----
    const size_t sz_we = (size_t)E_PAD * 1024 * 2;   // 246 MB
    int mode, T;
    if (ws_size >= fixed_end + sz_we + 1024) { mode = 1; T = NT64; }
    else {
        mode = 0;
        size_t per_tile = (size_t)64 * 1024 * 2;
        size_t extra = alignup((size_t)NN * 32 * 4);
        size_t avail = ws_size > fixed_end + extra + 4096
                     ? ws_size - fixed_end - extra - 4096 : per_tile;
        long t = (long)(avail / per_tile);
        if (t > NT64) t = NT64;
        if (t < 1) t = 1;
        T = (int)t;
    }
    bf16_t* w_e = nullptr;
    float* aggr = nullptr;
    if (mode == 1) {
        w_e = (bf16_t*)alloc(sz_we);
    } else {
        aggr = (float*)alloc((size_t)NN * 32 * 4);
        w_e  = (bf16_t*)alloc((size_t)T * 64 * 1024 * 2);
    }

    hipMemsetAsync(zbase, 0, zlen, stream);

    detect_all<<<32, 256, 0, stream>>>((const unsigned short*)d_in[2], ei, f32fl, idxfl);

    CvtArgs ca;
    for (int i = 0; i < N_FLT; ++i) {
        ca.src[i] = d_in[fidx[i]];
        ca.offs[i] = foffs[i];
        ca.n[i] = fn[i];
    }
    ca.dst = canon;
    ca.tot = tot;
    cvt_flat<<<(tot + 255) / 256, 256, 0, stream>>>(ca, f32fl);

    repack_idx<<<(EE + 255) / 256, 256, 0, stream>>>(ei, idxfl, srcb, dstb, cnti);
    scan_kernel<<<1, 256, 0, stream>>>(cnti, rowo, pos);
    scatter_rank<<<(E_PAD + 255) / 256, 256, 0, stream>>>(dstb, srcb, pos, rankb, src_s);

    misc_prep<<<(615936 + 255) / 256, 256, 0, stream>>>(c_k2w, k2t, c_k3w, k3t,
                                                        c_k3b, k3bp, c_x, c_fc1w,
                                                        c_fc1b, h_a);

    float* hc = h_a;
    float* hn = h_b;
    if (mode == 1) {
        fused_prep<<<NT64, 256, 0, stream>>>(c_ea, c_k1w, c_k1b, k2t, c_k2b,
                                             k3t, k3bp, w_e, rankb, 0, 1);
        for (int d = 0; d < 4; ++d) {
            gather_stream<<<(NN + 3) / 4, 256, 0, stream>>>(hc, w_e, src_s, rowo,
                                                            c_rw, c_cb, hn,
                                                            (d < 3) ? 1 : 0, d & 1);
            float* tmp = hc; hc = hn; hn = tmp;
        }
    } else {
        for (int d = 0; d < 4; ++d) {
            hipMemsetAsync(aggr, 0, (size_t)NN * 32 * 4, stream);
            for (int t0 = 0; t0 < NT64; t0 += T) {
                int tl = (t0 + T <= NT64) ? T : (NT64 - t0);
                fused_prep<<<tl, 256, 0, stream>>>(c_ea, c_k1w, c_k1b, k2t, c_k2b,
                                                   k3t, k3bp, w_e, rankb, t0, 0);
                int e0 = t0 * 64;
                int e1 = e0 + tl * 64; if (e1 > EE) e1 = EE;
                if (e1 > e0)
                    edge_scatter<<<(e1 - e0 + 3) / 4, 256, 0, stream>>>(hc, w_e, srcb, dstb,
                                                                        aggr, e0, e1);
            }
            node_update<<<NN * 32 / 256, 256, 0, stream>>>(hc, aggr, cnti, c_rw, c_cb, hn,
                                                           (d < 3) ? 1 : 0);
            float* tmp = hc; hc = hn; hn = tmp;
        }
    }

    head_kernel<<<(NN + 3) / 4, 256, 0, stream>>>(hc, c_fc2w, c_fc2b, c_fc3w, c_fc3b,
                                                  d_out, f32fl);
}